// Round 7
// baseline (363.242 us; speedup 1.0000x reference)
//
#include <hip/hip_runtime.h>
#include <hip/hip_bf16.h>

#define H2 16
#define HKV 8
#define DHEAD 128
#define HID 1024
#define NQ 2048

typedef unsigned short u16;
typedef __bf16 bf16x8 __attribute__((ext_vector_type(8)));
typedef float f32x4 __attribute__((ext_vector_type(4)));

__device__ __forceinline__ u16 f2bf(float x) {
    unsigned int u = __float_as_uint(x);
    unsigned int r = (u + 0x7fffu + ((u >> 16) & 1u)) >> 16;
    return (u16)r;
}
__device__ __forceinline__ float bf2f(u16 x) {
    return __uint_as_float(((unsigned int)x) << 16);
}

// pack two fp32 -> (bf16(hi)<<16)|bf16(lo)
__device__ __forceinline__ unsigned int pack_bf16(float hi, float lo) {
    unsigned int a = __float_as_uint(hi) + 0x8000u;
    unsigned int b = __float_as_uint(lo) + 0x8000u;
    return __builtin_amdgcn_perm(a, b, 0x07060302u);
}

__device__ __forceinline__ bf16x8 ld_frag(const u16* p) {
    bf16x8 r;
    *reinterpret_cast<uint4*>(&r) = *reinterpret_cast<const uint4*>(p);
    return r;
}

__device__ __forceinline__ void gload_lds16(const u16* g, u16* l) {
    __builtin_amdgcn_global_load_lds((const __attribute__((address_space(1))) void*)g,
                                     (__attribute__((address_space(3))) void*)l, 16, 0, 0);
}

// ---------------- cast x fp32 -> bf16 ----------------
__global__ __launch_bounds__(256) void cast_f32_bf16(const float* __restrict__ in,
                                                     u16* __restrict__ out, int n4) {
    int i = blockIdx.x * 256 + threadIdx.x;
    if (i < n4) {
        float4 v = reinterpret_cast<const float4*>(in)[i];
        ushort4 o;
        o.x = f2bf(v.x); o.y = f2bf(v.y); o.z = f2bf(v.z); o.w = f2bf(v.w);
        reinterpret_cast<ushort4*>(out)[i] = o;
    }
}

// ---------------- all 4 weight transposes in ONE launch ----------------
__global__ __launch_bounds__(256) void transpose_cast_all(const float* __restrict__ Wq,
                                                          const float* __restrict__ Wk,
                                                          const float* __restrict__ Wv,
                                                          const float* __restrict__ Wo,
                                                          u16* __restrict__ Wqkvb,
                                                          u16* __restrict__ Wob) {
    __shared__ u16 t[32][34];
    int bid = blockIdx.x;
    const float* in; u16* out; int K, N, k0, n0;
    if (bid < 2048) {
        in = Wq; out = Wqkvb; K = 1024; N = 2048;
        k0 = (bid & 31) * 32; n0 = (bid >> 5) * 32;
    } else if (bid < 3072) {
        int b = bid - 2048;
        in = Wk; out = Wqkvb + (size_t)2048 * 1024; K = 1024; N = 1024;
        k0 = (b & 31) * 32; n0 = (b >> 5) * 32;
    } else if (bid < 4096) {
        int b = bid - 3072;
        in = Wv; out = Wqkvb + (size_t)3072 * 1024; K = 1024; N = 1024;
        k0 = (b & 31) * 32; n0 = (b >> 5) * 32;
    } else {
        int b = bid - 4096;
        in = Wo; out = Wob; K = 2048; N = 1024;
        k0 = (b & 63) * 32; n0 = (b >> 6) * 32;
    }
    for (int c = threadIdx.x; c < 1024; c += 256) {
        int k = c >> 5, n = c & 31;
        t[k][n] = f2bf(in[(size_t)(k0 + k) * N + n0 + n]);
    }
    __syncthreads();
    for (int c = threadIdx.x; c < 1024; c += 256) {
        int n = c >> 5, k = c & 31;
        out[(size_t)(n0 + n) * K + k0 + k] = t[k][n];
    }
}

// ---------------- GEMM 128x128, BK=64 (two BK=32 slabs) ----------------
template <bool OUT_BF16>
__global__ __launch_bounds__(256) void gemm_bf16_t(const u16* __restrict__ A,
                                                   const u16* __restrict__ Bt,
                                                   void* __restrict__ Cv,
                                                   int M, int N, int K) {
    __shared__ u16 As[2][128 * 32];
    __shared__ u16 Bs[2][128 * 32];
    int tid = threadIdx.x;
    int lane = tid & 63, wave = tid >> 6;
    int quad = lane >> 4, l15 = lane & 15;
    int wr = wave >> 1, wc = wave & 1;
    int m0 = blockIdx.y * 128, n0 = blockIdx.x * 128;

    f32x4 zero = {0.f, 0.f, 0.f, 0.f};
    f32x4 acc[4][4];
    for (int i = 0; i < 4; i++)
        for (int j = 0; j < 4; j++) acc[i][j] = zero;

    int r0 = 16 * wave + (lane >> 2);
    int r1 = r0 + 64;
    int ks0 = (lane & 3) ^ ((r0 >> 1) & 3);
    int ks1 = (lane & 3) ^ ((r1 >> 1) & 3);
    const u16* ga0 = A + (size_t)(m0 + r0) * K + ks0 * 8;
    const u16* ga1 = A + (size_t)(m0 + r1) * K + ks1 * 8;
    const u16* gb0 = Bt + (size_t)(n0 + r0) * K + ks0 * 8;
    const u16* gb1 = Bt + (size_t)(n0 + r1) * K + ks1 * 8;

    int swz = (quad ^ ((l15 >> 1) & 3)) * 8;

    for (int k0 = 0; k0 < K; k0 += 64) {
        __syncthreads();
        #pragma unroll
        for (int s = 0; s < 2; s++) {
            gload_lds16(ga0 + k0 + s * 32, &As[s][wave * 512]);
            gload_lds16(ga1 + k0 + s * 32, &As[s][(wave + 4) * 512]);
            gload_lds16(gb0 + k0 + s * 32, &Bs[s][wave * 512]);
            gload_lds16(gb1 + k0 + s * 32, &Bs[s][(wave + 4) * 512]);
        }
        __syncthreads();
        #pragma unroll
        for (int s = 0; s < 2; s++) {
            bf16x8 a[4], b[4];
            #pragma unroll
            for (int i = 0; i < 4; i++) a[i] = ld_frag(&As[s][(64 * wr + 16 * i + l15) * 32 + swz]);
            #pragma unroll
            for (int j = 0; j < 4; j++) b[j] = ld_frag(&Bs[s][(64 * wc + 16 * j + l15) * 32 + swz]);
            #pragma unroll
            for (int i = 0; i < 4; i++)
                #pragma unroll
                for (int j = 0; j < 4; j++)
                    acc[i][j] = __builtin_amdgcn_mfma_f32_16x16x32_bf16(a[i], b[j], acc[i][j], 0, 0, 0);
        }
    }
    for (int i = 0; i < 4; i++) {
        int rowb = m0 + 64 * wr + 16 * i + quad * 4;
        for (int j = 0; j < 4; j++) {
            int col = n0 + 64 * wc + 16 * j + l15;
            for (int r = 0; r < 4; r++) {
                if (OUT_BF16)
                    ((u16*)Cv)[(size_t)(rowb + r) * N + col] = f2bf(acc[i][j][r]);
                else
                    ((float*)Cv)[(size_t)(rowb + r) * N + col] = acc[i][j][r];
            }
        }
    }
}

// ---------------- GEMM 128x64, BK=64 (Wo) ----------------
__global__ __launch_bounds__(256) void gemm_bf16_n64(const u16* __restrict__ A,
                                                     const u16* __restrict__ Bt,
                                                     float* __restrict__ C,
                                                     int M, int N, int K) {
    __shared__ u16 As[2][128 * 32];
    __shared__ u16 Bs[2][64 * 32];
    int tid = threadIdx.x;
    int lane = tid & 63, wave = tid >> 6;
    int quad = lane >> 4, l15 = lane & 15;
    int m0 = blockIdx.y * 128, n0 = blockIdx.x * 64;

    f32x4 zero = {0.f, 0.f, 0.f, 0.f};
    f32x4 acc[2][4];
    for (int i = 0; i < 2; i++)
        for (int j = 0; j < 4; j++) acc[i][j] = zero;

    int ra0 = 32 * wave + (lane >> 2);
    int ra1 = ra0 + 16;
    int rb  = 16 * wave + (lane >> 2);
    int ksa0 = (lane & 3) ^ ((ra0 >> 1) & 3);
    int ksa1 = (lane & 3) ^ ((ra1 >> 1) & 3);
    int ksb  = (lane & 3) ^ ((rb >> 1) & 3);
    const u16* ga0 = A + (size_t)(m0 + ra0) * K + ksa0 * 8;
    const u16* ga1 = A + (size_t)(m0 + ra1) * K + ksa1 * 8;
    const u16* gb  = Bt + (size_t)(n0 + rb) * K + ksb * 8;

    int swz = (quad ^ ((l15 >> 1) & 3)) * 8;

    for (int k0 = 0; k0 < K; k0 += 64) {
        __syncthreads();
        #pragma unroll
        for (int s = 0; s < 2; s++) {
            gload_lds16(ga0 + k0 + s * 32, &As[s][(2 * wave) * 512]);
            gload_lds16(ga1 + k0 + s * 32, &As[s][(2 * wave + 1) * 512]);
            gload_lds16(gb + k0 + s * 32, &Bs[s][wave * 512]);
        }
        __syncthreads();
        #pragma unroll
        for (int s = 0; s < 2; s++) {
            bf16x8 a[2], b[4];
            #pragma unroll
            for (int i = 0; i < 2; i++) a[i] = ld_frag(&As[s][(32 * wave + 16 * i + l15) * 32 + swz]);
            #pragma unroll
            for (int j = 0; j < 4; j++) b[j] = ld_frag(&Bs[s][(16 * j + l15) * 32 + swz]);
            #pragma unroll
            for (int i = 0; i < 2; i++)
                #pragma unroll
                for (int j = 0; j < 4; j++)
                    acc[i][j] = __builtin_amdgcn_mfma_f32_16x16x32_bf16(a[i], b[j], acc[i][j], 0, 0, 0);
        }
    }
    for (int i = 0; i < 2; i++) {
        int rowb = m0 + 32 * wave + 16 * i + quad * 4;
        for (int j = 0; j < 4; j++) {
            int col = n0 + 16 * j + l15;
            for (int r = 0; r < 4; r++)
                C[(size_t)(rowb + r) * N + col] = acc[i][j][r];
        }
    }
}

// ---------------- fused RMSNorm + RoPE ----------------
__global__ __launch_bounds__(256) void norm_rope_qk(const u16* __restrict__ qkv,
                                                    const float* __restrict__ cosp,
                                                    const float* __restrict__ sinp,
                                                    const float* __restrict__ qnw,
                                                    const float* __restrict__ knw,
                                                    u16* __restrict__ Qb,
                                                    u16* __restrict__ Kb,
                                                    int T, float qscale) {
    int wave = threadIdx.x >> 6, lane = threadIdx.x & 63;
    int wid = blockIdx.x * 4 + wave;
    int t = wid / 24, unit = wid % 24;
    if (t >= T) return;
    bool isq = unit < 16;
    int coloff = isq ? unit * 128 : 2048 + (unit - 16) * 128;
    const float* w = isq ? qnw : knw;
    float outscale = isq ? qscale : 1.0f;
    u16* out = isq ? (Qb + ((size_t)unit * T + t) * 128)
                   : (Kb + ((size_t)(unit - 16) * T + t) * 128);
    const u16* r = qkv + (size_t)t * 4096 + coloff;
    float v1 = bf2f(r[lane]), v2 = bf2f(r[lane + 64]);
    float ss = v1 * v1 + v2 * v2;
    for (int off = 1; off < 64; off <<= 1) ss += __shfl_xor(ss, off);
    float inv = rsqrtf(ss * (1.f / 128.f) + 1e-6f);
    float n1 = v1 * inv * w[lane], n2 = v2 * inv * w[lane + 64];
    float c = cosp[(size_t)t * 64 + lane], s = sinp[(size_t)t * 64 + lane];
    float o1 = (n1 * c - n2 * s) * outscale;
    float o2 = (n1 * s + n2 * c) * outscale;
    out[lane] = f2bf(o1);
    out[lane + 64] = f2bf(o2);
}

// ---------------- V transpose ----------------
__global__ __launch_bounds__(256) void v_transpose(const u16* __restrict__ qkv,
                                                   u16* __restrict__ Vbt, int T) {
    __shared__ u16 tt[128][72];
    int h = blockIdx.y, t0 = blockIdx.x * 64;
    for (int c = threadIdx.x; c < 8192; c += 256) {
        int r = c >> 7, d = c & 127;
        tt[d][r] = qkv[(size_t)(t0 + r) * 4096 + 3072 + h * 128 + d];
    }
    __syncthreads();
    for (int c = threadIdx.x; c < 8192; c += 256) {
        int d = c >> 6, r = c & 63;
        Vbt[((size_t)h * 128 + d) * T + t0 + r] = tt[d][r];
    }
}

// ---------------- causal MFMA flash attention: R2 code + XCD swizzle + setprio ----------------
// Wave (qw, sh): qw = wave&3 owns q-rows [16qw,16qw+16); sh = wave>>2 owns s-half sh of
// every 64-wide KV tile. Softmax/rescale/merge numerics are byte-identical to R2 (159us,
// verified). Two zero-numerics additions:
//  (1) 1-D grid XCD swizzle: bid%8 == kvh (assumes round-robin bid->XCD dispatch), so
//      each XCD's 4MB L2 holds its KV head's entire K+V (2MB) -> stage loads hit L2,
//      shrinking the per-iter barrier vmcnt drain. FETCH_SIZE is the diagnostic.
//  (2) s_setprio(1) around QK/PV MFMA clusters (T5).
__global__ __launch_bounds__(512, 4) void flash_attn(const u16* __restrict__ Qb,
                                                     const u16* __restrict__ Kb,
                                                     const u16* __restrict__ Vbt,
                                                     u16* __restrict__ attn, int T) {
    __shared__ u16 Ks[2][64 * 128];
    __shared__ u16 Vt[2][128 * 64];
    __shared__ u16 Ps[64 * 64];
    __shared__ float Ms[4][2][16];
    __shared__ float Ls[4][2][16];
    int tid = threadIdx.x;
    int lane = tid & 63, wave = tid >> 6;   // 0..7
    int qw = wave & 3, sh = wave >> 2;
    int quad = lane >> 4, l15 = lane & 15;
    int swb8 = (l15 & 7) * 8;
    // XCD swizzle: linear bid -> (h, j) with bid%8 == h>>1 (= kvh = XCD id)
    int bid = (int)blockIdx.x;
    int xcd = bid & 7, n = bid >> 3;
    int h = xcd * 2 + (n >> 5);
    int j = n & 31;             // 0..31
    int kvh = h >> 1;           // == xcd

    const u16* kbase = Kb + (size_t)kvh * T * 128;
    const u16* vbase = Vbt + (size_t)kvh * 128 * T;

    int krow_ = lane >> 4;
    int kseg_ = lane & 15;
    int vrow_ = lane >> 3;
    int vseg_ = lane & 7;

    auto stage = [&](int s0, int b) {
        #pragma unroll
        for (int i = 0; i < 2; i++) {
            int ch = wave * 2 + i;
            int r = ch * 4 + krow_;
            int s = kseg_ ^ (r & 7);
            gload_lds16(kbase + (size_t)(s0 + r) * 128 + s * 8, &Ks[b][ch * 512]);
        }
        #pragma unroll
        for (int i = 0; i < 2; i++) {
            int ch = wave * 2 + i;
            int d = ch * 8 + vrow_;
            int s = vseg_ ^ (d & 7);
            gload_lds16(vbase + (size_t)d * T + s0 + s * 8, &Vt[b][ch * 512]);
        }
    };

    bf16x8 onesf;
    #pragma unroll
    for (int i = 0; i < 8; i++) onesf[i] = (__bf16)1.0f;
    f32x4 zero = {0.f, 0.f, 0.f, 0.f};
    const float L2E = 1.44269504f;

    for (int pass = 0; pass < 2; ++pass) {
        int qt = pass == 0 ? (63 - j) : j;
        int q0 = qt * 64;

        bf16x8 qf[4];
        {
            const u16* qp = Qb + ((size_t)h * T + q0 + 16 * qw + l15) * 128 + quad * 8;
            #pragma unroll
            for (int kk = 0; kk < 4; kk++) qf[kk] = ld_frag(qp + kk * 32);
        }

        float m_i = -3.0e38f;       // per-lane: q-row = 16*qw + l15
        f32x4 lsum = zero;          // C-layout rows: q = 16*qw + quad*4 + r
        f32x4 o[8];
        for (int dt = 0; dt < 8; dt++) o[dt] = zero;

        int ntiles = qt + 1;
        stage(0, 0);
        __syncthreads();  // tile 0 resident

        for (int it = 0; it < ntiles; ++it) {
            int b = it & 1;
            if (it + 1 < ntiles) stage((it + 1) * 64, 1 - b);  // async into other buffer
            bool diag = (it == qt);
            // diagonal tile: sh=1 waves with q-rows entirely < 32 are fully masked -> skip
            if (!(diag && sh == 1 && qw < 2)) {
                // S^T: A=K (own s-half), B=Q. scT[jt][r]: s = sh*32+jt*16+quad*4+r, q = 16qw+l15
                f32x4 scT[2];
                scT[0] = zero; scT[1] = zero;
                __builtin_amdgcn_s_setprio(1);
                #pragma unroll
                for (int kk = 0; kk < 4; kk++)
                    #pragma unroll
                    for (int jt = 0; jt < 2; jt++) {
                        bf16x8 kfrag = ld_frag(&Ks[b][(sh * 32 + jt * 16 + l15) * 128 + ((kk * 32 + quad * 8) ^ swb8)]);
                        scT[jt] = __builtin_amdgcn_mfma_f32_16x16x32_bf16(kfrag, qf[kk], scT[jt], 0, 0, 0);
                    }
                __builtin_amdgcn_s_setprio(0);

                if (diag) {  // mask s > q
                    int qloc = 16 * qw + l15;
                    #pragma unroll
                    for (int jt = 0; jt < 2; jt++)
                        for (int r = 0; r < 4; r++)
                            if (sh * 32 + jt * 16 + quad * 4 + r > qloc) scT[jt][r] = -1e30f;
                }

                // lane-local max over 8 scores (same q), then 2-step butterfly across quads
                float mt = scT[0][0];
                #pragma unroll
                for (int jt = 0; jt < 2; jt++)
                    for (int r = 0; r < 4; r++) mt = fmaxf(mt, scT[jt][r]);
                mt = fmaxf(mt, __shfl_xor(mt, 16));
                mt = fmaxf(mt, __shfl_xor(mt, 32));
                float mnew = fmaxf(m_i, mt);
                float alpha = __expf(m_i - mnew);
                m_i = mnew;
                float mls = mnew * L2E;

                #pragma unroll
                for (int jt = 0; jt < 2; jt++)
                    for (int r = 0; r < 4; r++)
                        scT[jt][r] = exp2f(fmaf(scT[jt][r], L2E, -mls));

                // P^T -> Ps[q][s]: wave writes its own (16q x 32s) quadrant
                {
                    int prow = 16 * qw + l15;
                    #pragma unroll
                    for (int jt = 0; jt < 2; jt++) {
                        int s8 = sh * 4 + 2 * jt + (quad >> 1);
                        uint2 wv;
                        wv.x = pack_bf16(scT[jt][1], scT[jt][0]);
                        wv.y = pack_bf16(scT[jt][3], scT[jt][2]);
                        *reinterpret_cast<uint2*>(&Ps[prow * 64 + (s8 ^ (l15 & 7)) * 8 + (quad & 1) * 4]) = wv;
                    }
                }

                // alpha-skip: rescale only when some lane's max advanced
                if (__any(alpha != 1.0f)) {
                    float av[4];
                    #pragma unroll
                    for (int r = 0; r < 4; r++) av[r] = __shfl(alpha, quad * 4 + r);
                    #pragma unroll
                    for (int r = 0; r < 4; r++) lsum[r] *= av[r];
                    #pragma unroll
                    for (int dt = 0; dt < 8; dt++)
                        for (int r = 0; r < 4; r++) o[dt][r] *= av[r];
                }

                asm volatile("s_waitcnt lgkmcnt(0)" ::: "memory");  // wave-private Ps quadrant ordering

                __builtin_amdgcn_s_setprio(1);
                bf16x8 pa = ld_frag(&Ps[(16 * qw + l15) * 64 + (((sh * 4 + quad) ^ (l15 & 7)) * 8)]);
                lsum = __builtin_amdgcn_mfma_f32_16x16x32_bf16(pa, onesf, lsum, 0, 0, 0);
                #pragma unroll
                for (int dt = 0; dt < 8; dt++) {
                    bf16x8 vb = ld_frag(&Vt[b][(dt * 16 + l15) * 64 + (((sh * 4 + quad) * 8) ^ swb8)]);
                    o[dt] = __builtin_amdgcn_mfma_f32_16x16x32_bf16(pa, vb, o[dt], 0, 0, 0);
                }
                __builtin_amdgcn_s_setprio(0);
            }
            __syncthreads();  // drains next-tile loads + buffer handoff
        }

        // ---- merge the two s-halves (waves sh=0/1 with same qw) ----
        if (quad == 0) Ms[qw][sh][l15] = m_i;
        if (l15 == 0) {
            #pragma unroll
            for (int r = 0; r < 4; r++) Ls[qw][sh][quad * 4 + r] = lsum[r];
        }
        __syncthreads();
        float M4[4], wS[4];
        #pragma unroll
        for (int r = 0; r < 4; r++) {
            float mS = Ms[qw][sh][quad * 4 + r];
            float mO = Ms[qw][sh ^ 1][quad * 4 + r];
            M4[r] = fmaxf(mS, mO);
            wS[r] = __expf(mS - M4[r]);
        }
        float* scr = reinterpret_cast<float*>(&Ks[0][0]);  // 32KB: [qw][d:128][q':16]
        if (sh == 1) {
            #pragma unroll
            for (int dt = 0; dt < 8; dt++)
                #pragma unroll
                for (int r = 0; r < 4; r++)
                    scr[qw * 2048 + (dt * 16 + l15) * 16 + ((quad * 4 + r) ^ l15)] = o[dt][r] * wS[r];
        }
        __syncthreads();
        if (sh == 0) {
            float inv[4];
            #pragma unroll
            for (int r = 0; r < 4; r++) {
                float mO = Ms[qw][1][quad * 4 + r];
                float wO = __expf(mO - M4[r]);
                float l = lsum[r] * wS[r] + Ls[qw][1][quad * 4 + r] * wO;
                inv[r] = 1.f / l;
            }
            #pragma unroll
            for (int dt = 0; dt < 8; dt++)
                #pragma unroll
                for (int r = 0; r < 4; r++) {
                    float val = (o[dt][r] * wS[r] +
                                 scr[qw * 2048 + (dt * 16 + l15) * 16 + ((quad * 4 + r) ^ l15)]) * inv[r];
                    int row = q0 + 16 * qw + quad * 4 + r;
                    attn[(size_t)row * NQ + h * DHEAD + dt * 16 + l15] = f2bf(val);
                }
        }
        __syncthreads();  // scr/Ms/Ls free before next pass restages Ks[0]
    }
}

extern "C" void kernel_launch(void* const* d_in, const int* in_sizes, int n_in,
                              void* d_out, int out_size, void* d_ws, size_t ws_size,
                              hipStream_t stream) {
    const float* x    = (const float*)d_in[0];
    const float* cosp = (const float*)d_in[1];
    const float* sinp = (const float*)d_in[2];
    const float* Wq   = (const float*)d_in[3];
    const float* Wk   = (const float*)d_in[4];
    const float* Wv   = (const float*)d_in[5];
    const float* Wo   = (const float*)d_in[6];
    const float* qnw  = (const float*)d_in[7];
    const float* knw  = (const float*)d_in[8];
    float* out = (float*)d_out;
    const int T = in_sizes[1] / 64;  // 4096

    char* ws = (char*)d_ws;
    size_t off = 0;
    auto alloc = [&](size_t bytes) {
        char* p = ws + off;
        off += (bytes + 255) & ~(size_t)255;
        return p;
    };
    u16*   xb     = (u16*)alloc((size_t)T * HID * 2);
    u16*   Wqkvb  = (u16*)alloc((size_t)4096 * HID * 2);
    u16*   Wob    = (u16*)alloc((size_t)HID * NQ * 2);
    u16*   qkvb   = (u16*)alloc((size_t)T * 4096 * 2);
    u16*   Qb     = (u16*)alloc((size_t)H2 * T * DHEAD * 2);
    u16*   Kb     = (u16*)alloc((size_t)HKV * T * DHEAD * 2);
    u16*   Vbt    = (u16*)alloc((size_t)HKV * DHEAD * T * 2);
    u16*   attn   = (u16*)alloc((size_t)T * NQ * 2);

    cast_f32_bf16<<<(T * HID / 4 + 255) / 256, 256, 0, stream>>>(x, xb, T * HID / 4);
    transpose_cast_all<<<6144, 256, 0, stream>>>(Wq, Wk, Wv, Wo, Wqkvb, Wob);

    gemm_bf16_t<true><<<dim3(4096 / 128, T / 128), 256, 0, stream>>>(xb, Wqkvb, qkvb, T, 4096, HID);

    const float scale = 0.08838834764831845f;  // 128^-0.5 folded into Q
    norm_rope_qk<<<T * 24 / 4, 256, 0, stream>>>(qkvb, cosp, sinp, qnw, knw, Qb, Kb, T, scale);
    v_transpose<<<dim3(T / 64, HKV), 256, 0, stream>>>(qkvb, Vbt, T);

    flash_attn<<<dim3(512), 512, 0, stream>>>(Qb, Kb, Vbt, attn, T);

    gemm_bf16_n64<<<dim3(HID / 64, T / 128), 256, 0, stream>>>(attn, Wob, out, T, HID, NQ);
}

// Round 8
// 362.230 us; speedup vs baseline: 1.0028x; 1.0028x over previous
//
#include <hip/hip_runtime.h>
#include <hip/hip_bf16.h>

#define H2 16
#define HKV 8
#define DHEAD 128
#define HID 1024
#define NQ 2048

typedef unsigned short u16;
typedef __bf16 bf16x8 __attribute__((ext_vector_type(8)));
typedef float f32x4 __attribute__((ext_vector_type(4)));

__device__ __forceinline__ u16 f2bf(float x) {
    unsigned int u = __float_as_uint(x);
    unsigned int r = (u + 0x7fffu + ((u >> 16) & 1u)) >> 16;
    return (u16)r;
}
__device__ __forceinline__ float bf2f(u16 x) {
    return __uint_as_float(((unsigned int)x) << 16);
}

// pack two fp32 -> (bf16(hi)<<16)|bf16(lo)
__device__ __forceinline__ unsigned int pack_bf16(float hi, float lo) {
    unsigned int a = __float_as_uint(hi) + 0x8000u;
    unsigned int b = __float_as_uint(lo) + 0x8000u;
    return __builtin_amdgcn_perm(a, b, 0x07060302u);
}

__device__ __forceinline__ bf16x8 ld_frag(const u16* p) {
    bf16x8 r;
    *reinterpret_cast<uint4*>(&r) = *reinterpret_cast<const uint4*>(p);
    return r;
}

__device__ __forceinline__ void gload_lds16(const u16* g, u16* l) {
    __builtin_amdgcn_global_load_lds((const __attribute__((address_space(1))) void*)g,
                                     (__attribute__((address_space(3))) void*)l, 16, 0, 0);
}

// ---------------- cast x fp32 -> bf16 ----------------
__global__ __launch_bounds__(256) void cast_f32_bf16(const float* __restrict__ in,
                                                     u16* __restrict__ out, int n4) {
    int i = blockIdx.x * 256 + threadIdx.x;
    if (i < n4) {
        float4 v = reinterpret_cast<const float4*>(in)[i];
        ushort4 o;
        o.x = f2bf(v.x); o.y = f2bf(v.y); o.z = f2bf(v.z); o.w = f2bf(v.w);
        reinterpret_cast<ushort4*>(out)[i] = o;
    }
}

// ---------------- all 4 weight transposes in ONE launch ----------------
__global__ __launch_bounds__(256) void transpose_cast_all(const float* __restrict__ Wq,
                                                          const float* __restrict__ Wk,
                                                          const float* __restrict__ Wv,
                                                          const float* __restrict__ Wo,
                                                          u16* __restrict__ Wqkvb,
                                                          u16* __restrict__ Wob) {
    __shared__ u16 t[32][34];
    int bid = blockIdx.x;
    const float* in; u16* out; int K, N, k0, n0;
    if (bid < 2048) {
        in = Wq; out = Wqkvb; K = 1024; N = 2048;
        k0 = (bid & 31) * 32; n0 = (bid >> 5) * 32;
    } else if (bid < 3072) {
        int b = bid - 2048;
        in = Wk; out = Wqkvb + (size_t)2048 * 1024; K = 1024; N = 1024;
        k0 = (b & 31) * 32; n0 = (b >> 5) * 32;
    } else if (bid < 4096) {
        int b = bid - 3072;
        in = Wv; out = Wqkvb + (size_t)3072 * 1024; K = 1024; N = 1024;
        k0 = (b & 31) * 32; n0 = (b >> 5) * 32;
    } else {
        int b = bid - 4096;
        in = Wo; out = Wob; K = 2048; N = 1024;
        k0 = (b & 63) * 32; n0 = (b >> 6) * 32;
    }
    for (int c = threadIdx.x; c < 1024; c += 256) {
        int k = c >> 5, n = c & 31;
        t[k][n] = f2bf(in[(size_t)(k0 + k) * N + n0 + n]);
    }
    __syncthreads();
    for (int c = threadIdx.x; c < 1024; c += 256) {
        int n = c >> 5, k = c & 31;
        out[(size_t)(n0 + n) * K + k0 + k] = t[k][n];
    }
}

// ---------------- GEMM 128x128, BK=64 (two BK=32 slabs) ----------------
template <bool OUT_BF16>
__global__ __launch_bounds__(256) void gemm_bf16_t(const u16* __restrict__ A,
                                                   const u16* __restrict__ Bt,
                                                   void* __restrict__ Cv,
                                                   int M, int N, int K) {
    __shared__ u16 As[2][128 * 32];
    __shared__ u16 Bs[2][128 * 32];
    int tid = threadIdx.x;
    int lane = tid & 63, wave = tid >> 6;
    int quad = lane >> 4, l15 = lane & 15;
    int wr = wave >> 1, wc = wave & 1;
    int m0 = blockIdx.y * 128, n0 = blockIdx.x * 128;

    f32x4 zero = {0.f, 0.f, 0.f, 0.f};
    f32x4 acc[4][4];
    for (int i = 0; i < 4; i++)
        for (int j = 0; j < 4; j++) acc[i][j] = zero;

    int r0 = 16 * wave + (lane >> 2);
    int r1 = r0 + 64;
    int ks0 = (lane & 3) ^ ((r0 >> 1) & 3);
    int ks1 = (lane & 3) ^ ((r1 >> 1) & 3);
    const u16* ga0 = A + (size_t)(m0 + r0) * K + ks0 * 8;
    const u16* ga1 = A + (size_t)(m0 + r1) * K + ks1 * 8;
    const u16* gb0 = Bt + (size_t)(n0 + r0) * K + ks0 * 8;
    const u16* gb1 = Bt + (size_t)(n0 + r1) * K + ks1 * 8;

    int swz = (quad ^ ((l15 >> 1) & 3)) * 8;

    for (int k0 = 0; k0 < K; k0 += 64) {
        __syncthreads();
        #pragma unroll
        for (int s = 0; s < 2; s++) {
            gload_lds16(ga0 + k0 + s * 32, &As[s][wave * 512]);
            gload_lds16(ga1 + k0 + s * 32, &As[s][(wave + 4) * 512]);
            gload_lds16(gb0 + k0 + s * 32, &Bs[s][wave * 512]);
            gload_lds16(gb1 + k0 + s * 32, &Bs[s][(wave + 4) * 512]);
        }
        __syncthreads();
        #pragma unroll
        for (int s = 0; s < 2; s++) {
            bf16x8 a[4], b[4];
            #pragma unroll
            for (int i = 0; i < 4; i++) a[i] = ld_frag(&As[s][(64 * wr + 16 * i + l15) * 32 + swz]);
            #pragma unroll
            for (int j = 0; j < 4; j++) b[j] = ld_frag(&Bs[s][(64 * wc + 16 * j + l15) * 32 + swz]);
            #pragma unroll
            for (int i = 0; i < 4; i++)
                #pragma unroll
                for (int j = 0; j < 4; j++)
                    acc[i][j] = __builtin_amdgcn_mfma_f32_16x16x32_bf16(a[i], b[j], acc[i][j], 0, 0, 0);
        }
    }
    for (int i = 0; i < 4; i++) {
        int rowb = m0 + 64 * wr + 16 * i + quad * 4;
        for (int j = 0; j < 4; j++) {
            int col = n0 + 64 * wc + 16 * j + l15;
            for (int r = 0; r < 4; r++) {
                if (OUT_BF16)
                    ((u16*)Cv)[(size_t)(rowb + r) * N + col] = f2bf(acc[i][j][r]);
                else
                    ((float*)Cv)[(size_t)(rowb + r) * N + col] = acc[i][j][r];
            }
        }
    }
}

// ---------------- GEMM 128x64, BK=64 (Wo); A = attn in HEAD-MAJOR [16][T][128] ----------------
// Logical A[t][c] (c = h*128+d) lives at A[(c>>7)*M*128 + t*128 + (c&127)].
// All staged 16B chunks are 8-aligned with (chunk_col & 127) <= 120, so no chunk
// straddles a head block and the per-row XOR staging swizzle carries over unchanged.
__global__ __launch_bounds__(256) void gemm_bf16_n64(const u16* __restrict__ A,
                                                     const u16* __restrict__ Bt,
                                                     float* __restrict__ C,
                                                     int M, int N, int K) {
    __shared__ u16 As[2][128 * 32];
    __shared__ u16 Bs[2][64 * 32];
    int tid = threadIdx.x;
    int lane = tid & 63, wave = tid >> 6;
    int quad = lane >> 4, l15 = lane & 15;
    int m0 = blockIdx.y * 128, n0 = blockIdx.x * 64;

    f32x4 zero = {0.f, 0.f, 0.f, 0.f};
    f32x4 acc[2][4];
    for (int i = 0; i < 2; i++)
        for (int j = 0; j < 4; j++) acc[i][j] = zero;

    int ra0 = 32 * wave + (lane >> 2);
    int ra1 = ra0 + 16;
    int rb  = 16 * wave + (lane >> 2);
    int ksa0 = (lane & 3) ^ ((ra0 >> 1) & 3);
    int ksa1 = (lane & 3) ^ ((ra1 >> 1) & 3);
    int ksb  = (lane & 3) ^ ((rb >> 1) & 3);
    const u16* ga0 = A + (size_t)(m0 + ra0) * 128 + ksa0 * 8;   // + head-block base per k0
    const u16* ga1 = A + (size_t)(m0 + ra1) * 128 + ksa1 * 8;
    const u16* gb  = Bt + (size_t)(n0 + rb) * K + ksb * 8;

    int swz = (quad ^ ((l15 >> 1) & 3)) * 8;

    for (int k0 = 0; k0 < K; k0 += 64) {
        size_t hoff = (size_t)(k0 >> 7) * (size_t)M * 128 + (k0 & 64);
        __syncthreads();
        #pragma unroll
        for (int s = 0; s < 2; s++) {
            gload_lds16(ga0 + hoff + s * 32, &As[s][(2 * wave) * 512]);
            gload_lds16(ga1 + hoff + s * 32, &As[s][(2 * wave + 1) * 512]);
            gload_lds16(gb + k0 + s * 32, &Bs[s][wave * 512]);
        }
        __syncthreads();
        #pragma unroll
        for (int s = 0; s < 2; s++) {
            bf16x8 a[2], b[4];
            #pragma unroll
            for (int i = 0; i < 2; i++) a[i] = ld_frag(&As[s][(32 * wave + 16 * i + l15) * 32 + swz]);
            #pragma unroll
            for (int j = 0; j < 4; j++) b[j] = ld_frag(&Bs[s][(16 * j + l15) * 32 + swz]);
            #pragma unroll
            for (int i = 0; i < 2; i++)
                #pragma unroll
                for (int j = 0; j < 4; j++)
                    acc[i][j] = __builtin_amdgcn_mfma_f32_16x16x32_bf16(a[i], b[j], acc[i][j], 0, 0, 0);
        }
    }
    for (int i = 0; i < 2; i++) {
        int rowb = m0 + 32 * wave + 16 * i + quad * 4;
        for (int j = 0; j < 4; j++) {
            int col = n0 + 16 * j + l15;
            for (int r = 0; r < 4; r++)
                C[(size_t)(rowb + r) * N + col] = acc[i][j][r];
        }
    }
}

// ---------------- fused RMSNorm + RoPE ----------------
__global__ __launch_bounds__(256) void norm_rope_qk(const u16* __restrict__ qkv,
                                                    const float* __restrict__ cosp,
                                                    const float* __restrict__ sinp,
                                                    const float* __restrict__ qnw,
                                                    const float* __restrict__ knw,
                                                    u16* __restrict__ Qb,
                                                    u16* __restrict__ Kb,
                                                    int T, float qscale) {
    int wave = threadIdx.x >> 6, lane = threadIdx.x & 63;
    int wid = blockIdx.x * 4 + wave;
    int t = wid / 24, unit = wid % 24;
    if (t >= T) return;
    bool isq = unit < 16;
    int coloff = isq ? unit * 128 : 2048 + (unit - 16) * 128;
    const float* w = isq ? qnw : knw;
    float outscale = isq ? qscale : 1.0f;
    u16* out = isq ? (Qb + ((size_t)unit * T + t) * 128)
                   : (Kb + ((size_t)(unit - 16) * T + t) * 128);
    const u16* r = qkv + (size_t)t * 4096 + coloff;
    float v1 = bf2f(r[lane]), v2 = bf2f(r[lane + 64]);
    float ss = v1 * v1 + v2 * v2;
    for (int off = 1; off < 64; off <<= 1) ss += __shfl_xor(ss, off);
    float inv = rsqrtf(ss * (1.f / 128.f) + 1e-6f);
    float n1 = v1 * inv * w[lane], n2 = v2 * inv * w[lane + 64];
    float c = cosp[(size_t)t * 64 + lane], s = sinp[(size_t)t * 64 + lane];
    float o1 = (n1 * c - n2 * s) * outscale;
    float o2 = (n1 * s + n2 * c) * outscale;
    out[lane] = f2bf(o1);
    out[lane + 64] = f2bf(o2);
}

// ---------------- V transpose ----------------
__global__ __launch_bounds__(256) void v_transpose(const u16* __restrict__ qkv,
                                                   u16* __restrict__ Vbt, int T) {
    __shared__ u16 tt[128][72];
    int h = blockIdx.y, t0 = blockIdx.x * 64;
    for (int c = threadIdx.x; c < 8192; c += 256) {
        int r = c >> 7, d = c & 127;
        tt[d][r] = qkv[(size_t)(t0 + r) * 4096 + 3072 + h * 128 + d];
    }
    __syncthreads();
    for (int c = threadIdx.x; c < 8192; c += 256) {
        int d = c >> 6, r = c & 63;
        Vbt[((size_t)h * 128 + d) * T + t0 + r] = tt[d][r];
    }
}

// ---------------- causal MFMA flash attention: R2 code + XCD swizzle + head-major out ----------------
// Wave (qw, sh): qw = wave&3 owns q-rows [16qw,16qw+16); sh = wave>>2 owns s-half sh of
// every 64-wide KV tile. Softmax/rescale/merge numerics byte-identical to R2 (159us).
//  (1) XCD swizzle kept (R7: FETCH 148->49MB, KV L2-resident per XCD).
//  (2) setprio REMOVED (R7 regression suspect; m190: hurts barrier-lockstep structures).
//  (3) attn output HEAD-MAJOR [h][T][128]: each block writes one contiguous 16KB region
//      per pass (was 64 x 256B pieces at 4KB stride) -> kills the 2.4-4x write
//      amplification (WRITE_SIZE 37.9-64.5MB vs 16MB ideal).
__global__ __launch_bounds__(512, 4) void flash_attn(const u16* __restrict__ Qb,
                                                     const u16* __restrict__ Kb,
                                                     const u16* __restrict__ Vbt,
                                                     u16* __restrict__ attn, int T) {
    __shared__ u16 Ks[2][64 * 128];
    __shared__ u16 Vt[2][128 * 64];
    __shared__ u16 Ps[64 * 64];
    __shared__ float Ms[4][2][16];
    __shared__ float Ls[4][2][16];
    int tid = threadIdx.x;
    int lane = tid & 63, wave = tid >> 6;   // 0..7
    int qw = wave & 3, sh = wave >> 2;
    int quad = lane >> 4, l15 = lane & 15;
    int swb8 = (l15 & 7) * 8;
    // XCD swizzle: linear bid -> (h, j) with bid%8 == h>>1 (= kvh = XCD id)
    int bid = (int)blockIdx.x;
    int xcd = bid & 7, n = bid >> 3;
    int h = xcd * 2 + (n >> 5);
    int j = n & 31;             // 0..31
    int kvh = h >> 1;           // == xcd

    const u16* kbase = Kb + (size_t)kvh * T * 128;
    const u16* vbase = Vbt + (size_t)kvh * 128 * T;

    int krow_ = lane >> 4;
    int kseg_ = lane & 15;
    int vrow_ = lane >> 3;
    int vseg_ = lane & 7;

    auto stage = [&](int s0, int b) {
        #pragma unroll
        for (int i = 0; i < 2; i++) {
            int ch = wave * 2 + i;
            int r = ch * 4 + krow_;
            int s = kseg_ ^ (r & 7);
            gload_lds16(kbase + (size_t)(s0 + r) * 128 + s * 8, &Ks[b][ch * 512]);
        }
        #pragma unroll
        for (int i = 0; i < 2; i++) {
            int ch = wave * 2 + i;
            int d = ch * 8 + vrow_;
            int s = vseg_ ^ (d & 7);
            gload_lds16(vbase + (size_t)d * T + s0 + s * 8, &Vt[b][ch * 512]);
        }
    };

    bf16x8 onesf;
    #pragma unroll
    for (int i = 0; i < 8; i++) onesf[i] = (__bf16)1.0f;
    f32x4 zero = {0.f, 0.f, 0.f, 0.f};
    const float L2E = 1.44269504f;

    for (int pass = 0; pass < 2; ++pass) {
        int qt = pass == 0 ? (63 - j) : j;
        int q0 = qt * 64;

        bf16x8 qf[4];
        {
            const u16* qp = Qb + ((size_t)h * T + q0 + 16 * qw + l15) * 128 + quad * 8;
            #pragma unroll
            for (int kk = 0; kk < 4; kk++) qf[kk] = ld_frag(qp + kk * 32);
        }

        float m_i = -3.0e38f;       // per-lane: q-row = 16*qw + l15
        f32x4 lsum = zero;          // C-layout rows: q = 16*qw + quad*4 + r
        f32x4 o[8];
        for (int dt = 0; dt < 8; dt++) o[dt] = zero;

        int ntiles = qt + 1;
        stage(0, 0);
        __syncthreads();  // tile 0 resident

        for (int it = 0; it < ntiles; ++it) {
            int b = it & 1;
            if (it + 1 < ntiles) stage((it + 1) * 64, 1 - b);  // async into other buffer
            bool diag = (it == qt);
            // diagonal tile: sh=1 waves with q-rows entirely < 32 are fully masked -> skip
            if (!(diag && sh == 1 && qw < 2)) {
                // S^T: A=K (own s-half), B=Q. scT[jt][r]: s = sh*32+jt*16+quad*4+r, q = 16qw+l15
                f32x4 scT[2];
                scT[0] = zero; scT[1] = zero;
                #pragma unroll
                for (int kk = 0; kk < 4; kk++)
                    #pragma unroll
                    for (int jt = 0; jt < 2; jt++) {
                        bf16x8 kfrag = ld_frag(&Ks[b][(sh * 32 + jt * 16 + l15) * 128 + ((kk * 32 + quad * 8) ^ swb8)]);
                        scT[jt] = __builtin_amdgcn_mfma_f32_16x16x32_bf16(kfrag, qf[kk], scT[jt], 0, 0, 0);
                    }

                if (diag) {  // mask s > q
                    int qloc = 16 * qw + l15;
                    #pragma unroll
                    for (int jt = 0; jt < 2; jt++)
                        for (int r = 0; r < 4; r++)
                            if (sh * 32 + jt * 16 + quad * 4 + r > qloc) scT[jt][r] = -1e30f;
                }

                // lane-local max over 8 scores (same q), then 2-step butterfly across quads
                float mt = scT[0][0];
                #pragma unroll
                for (int jt = 0; jt < 2; jt++)
                    for (int r = 0; r < 4; r++) mt = fmaxf(mt, scT[jt][r]);
                mt = fmaxf(mt, __shfl_xor(mt, 16));
                mt = fmaxf(mt, __shfl_xor(mt, 32));
                float mnew = fmaxf(m_i, mt);
                float alpha = __expf(m_i - mnew);
                m_i = mnew;
                float mls = mnew * L2E;

                #pragma unroll
                for (int jt = 0; jt < 2; jt++)
                    for (int r = 0; r < 4; r++)
                        scT[jt][r] = exp2f(fmaf(scT[jt][r], L2E, -mls));

                // P^T -> Ps[q][s]: wave writes its own (16q x 32s) quadrant
                {
                    int prow = 16 * qw + l15;
                    #pragma unroll
                    for (int jt = 0; jt < 2; jt++) {
                        int s8 = sh * 4 + 2 * jt + (quad >> 1);
                        uint2 wv;
                        wv.x = pack_bf16(scT[jt][1], scT[jt][0]);
                        wv.y = pack_bf16(scT[jt][3], scT[jt][2]);
                        *reinterpret_cast<uint2*>(&Ps[prow * 64 + (s8 ^ (l15 & 7)) * 8 + (quad & 1) * 4]) = wv;
                    }
                }

                // alpha-skip: rescale only when some lane's max advanced
                if (__any(alpha != 1.0f)) {
                    float av[4];
                    #pragma unroll
                    for (int r = 0; r < 4; r++) av[r] = __shfl(alpha, quad * 4 + r);
                    #pragma unroll
                    for (int r = 0; r < 4; r++) lsum[r] *= av[r];
                    #pragma unroll
                    for (int dt = 0; dt < 8; dt++)
                        for (int r = 0; r < 4; r++) o[dt][r] *= av[r];
                }

                asm volatile("s_waitcnt lgkmcnt(0)" ::: "memory");  // wave-private Ps quadrant ordering

                bf16x8 pa = ld_frag(&Ps[(16 * qw + l15) * 64 + (((sh * 4 + quad) ^ (l15 & 7)) * 8)]);
                lsum = __builtin_amdgcn_mfma_f32_16x16x32_bf16(pa, onesf, lsum, 0, 0, 0);
                #pragma unroll
                for (int dt = 0; dt < 8; dt++) {
                    bf16x8 vb = ld_frag(&Vt[b][(dt * 16 + l15) * 64 + (((sh * 4 + quad) * 8) ^ swb8)]);
                    o[dt] = __builtin_amdgcn_mfma_f32_16x16x32_bf16(pa, vb, o[dt], 0, 0, 0);
                }
            }
            __syncthreads();  // drains next-tile loads + buffer handoff
        }

        // ---- merge the two s-halves (waves sh=0/1 with same qw) ----
        if (quad == 0) Ms[qw][sh][l15] = m_i;
        if (l15 == 0) {
            #pragma unroll
            for (int r = 0; r < 4; r++) Ls[qw][sh][quad * 4 + r] = lsum[r];
        }
        __syncthreads();
        float M4[4], wS[4];
        #pragma unroll
        for (int r = 0; r < 4; r++) {
            float mS = Ms[qw][sh][quad * 4 + r];
            float mO = Ms[qw][sh ^ 1][quad * 4 + r];
            M4[r] = fmaxf(mS, mO);
            wS[r] = __expf(mS - M4[r]);
        }
        float* scr = reinterpret_cast<float*>(&Ks[0][0]);  // 32KB: [qw][d:128][q':16]
        if (sh == 1) {
            #pragma unroll
            for (int dt = 0; dt < 8; dt++)
                #pragma unroll
                for (int r = 0; r < 4; r++)
                    scr[qw * 2048 + (dt * 16 + l15) * 16 + ((quad * 4 + r) ^ l15)] = o[dt][r] * wS[r];
        }
        __syncthreads();
        if (sh == 0) {
            float inv[4];
            #pragma unroll
            for (int r = 0; r < 4; r++) {
                float mO = Ms[qw][1][quad * 4 + r];
                float wO = __expf(mO - M4[r]);
                float l = lsum[r] * wS[r] + Ls[qw][1][quad * 4 + r] * wO;
                inv[r] = 1.f / l;
            }
            #pragma unroll
            for (int dt = 0; dt < 8; dt++)
                #pragma unroll
                for (int r = 0; r < 4; r++) {
                    float val = (o[dt][r] * wS[r] +
                                 scr[qw * 2048 + (dt * 16 + l15) * 16 + ((quad * 4 + r) ^ l15)]) * inv[r];
                    int row = q0 + 16 * qw + quad * 4 + r;
                    attn[((size_t)h * T + row) * DHEAD + dt * 16 + l15] = f2bf(val);
                }
        }
        __syncthreads();  // scr/Ms/Ls free before next pass restages Ks[0]
    }
}

extern "C" void kernel_launch(void* const* d_in, const int* in_sizes, int n_in,
                              void* d_out, int out_size, void* d_ws, size_t ws_size,
                              hipStream_t stream) {
    const float* x    = (const float*)d_in[0];
    const float* cosp = (const float*)d_in[1];
    const float* sinp = (const float*)d_in[2];
    const float* Wq   = (const float*)d_in[3];
    const float* Wk   = (const float*)d_in[4];
    const float* Wv   = (const float*)d_in[5];
    const float* Wo   = (const float*)d_in[6];
    const float* qnw  = (const float*)d_in[7];
    const float* knw  = (const float*)d_in[8];
    float* out = (float*)d_out;
    const int T = in_sizes[1] / 64;  // 4096

    char* ws = (char*)d_ws;
    size_t off = 0;
    auto alloc = [&](size_t bytes) {
        char* p = ws + off;
        off += (bytes + 255) & ~(size_t)255;
        return p;
    };
    u16*   xb     = (u16*)alloc((size_t)T * HID * 2);
    u16*   Wqkvb  = (u16*)alloc((size_t)4096 * HID * 2);
    u16*   Wob    = (u16*)alloc((size_t)HID * NQ * 2);
    u16*   qkvb   = (u16*)alloc((size_t)T * 4096 * 2);
    u16*   Qb     = (u16*)alloc((size_t)H2 * T * DHEAD * 2);
    u16*   Kb     = (u16*)alloc((size_t)HKV * T * DHEAD * 2);
    u16*   Vbt    = (u16*)alloc((size_t)HKV * DHEAD * T * 2);
    u16*   attn   = (u16*)alloc((size_t)T * NQ * 2);   // head-major [H2][T][128]

    cast_f32_bf16<<<(T * HID / 4 + 255) / 256, 256, 0, stream>>>(x, xb, T * HID / 4);
    transpose_cast_all<<<6144, 256, 0, stream>>>(Wq, Wk, Wv, Wo, Wqkvb, Wob);

    gemm_bf16_t<true><<<dim3(4096 / 128, T / 128), 256, 0, stream>>>(xb, Wqkvb, qkvb, T, 4096, HID);

    const float scale = 0.08838834764831845f;  // 128^-0.5 folded into Q
    norm_rope_qk<<<T * 24 / 4, 256, 0, stream>>>(qkvb, cosp, sinp, qnw, knw, Qb, Kb, T, scale);
    v_transpose<<<dim3(T / 64, HKV), 256, 0, stream>>>(qkvb, Vbt, T);

    flash_attn<<<dim3(512), 512, 0, stream>>>(Qb, Kb, Vbt, attn, T);

    gemm_bf16_n64<<<dim3(HID / 64, T / 128), 256, 0, stream>>>(attn, Wob, out, T, HID, NQ);
}

// Round 9
// 343.055 us; speedup vs baseline: 1.0588x; 1.0559x over previous
//
#include <hip/hip_runtime.h>
#include <hip/hip_bf16.h>

#define H2 16
#define HKV 8
#define DHEAD 128
#define HID 1024
#define NQ 2048

typedef unsigned short u16;
typedef __bf16 bf16x8 __attribute__((ext_vector_type(8)));
typedef float f32x4 __attribute__((ext_vector_type(4)));

__device__ __forceinline__ u16 f2bf(float x) {
    unsigned int u = __float_as_uint(x);
    unsigned int r = (u + 0x7fffu + ((u >> 16) & 1u)) >> 16;
    return (u16)r;
}
__device__ __forceinline__ float bf2f(u16 x) {
    return __uint_as_float(((unsigned int)x) << 16);
}

// pack two fp32 -> (bf16(hi)<<16)|bf16(lo)
__device__ __forceinline__ unsigned int pack_bf16(float hi, float lo) {
    unsigned int a = __float_as_uint(hi) + 0x8000u;
    unsigned int b = __float_as_uint(lo) + 0x8000u;
    return __builtin_amdgcn_perm(a, b, 0x07060302u);
}

__device__ __forceinline__ bf16x8 ld_frag(const u16* p) {
    bf16x8 r;
    *reinterpret_cast<uint4*>(&r) = *reinterpret_cast<const uint4*>(p);
    return r;
}

__device__ __forceinline__ void gload_lds16(const u16* g, u16* l) {
    __builtin_amdgcn_global_load_lds((const __attribute__((address_space(1))) void*)g,
                                     (__attribute__((address_space(3))) void*)l, 16, 0, 0);
}

// ---------------- cast x fp32 -> bf16 ----------------
__global__ __launch_bounds__(256) void cast_f32_bf16(const float* __restrict__ in,
                                                     u16* __restrict__ out, int n4) {
    int i = blockIdx.x * 256 + threadIdx.x;
    if (i < n4) {
        float4 v = reinterpret_cast<const float4*>(in)[i];
        ushort4 o;
        o.x = f2bf(v.x); o.y = f2bf(v.y); o.z = f2bf(v.z); o.w = f2bf(v.w);
        reinterpret_cast<ushort4*>(out)[i] = o;
    }
}

// ---------------- all 4 weight transposes in ONE launch ----------------
__global__ __launch_bounds__(256) void transpose_cast_all(const float* __restrict__ Wq,
                                                          const float* __restrict__ Wk,
                                                          const float* __restrict__ Wv,
                                                          const float* __restrict__ Wo,
                                                          u16* __restrict__ Wqkvb,
                                                          u16* __restrict__ Wob) {
    __shared__ u16 t[32][34];
    int bid = blockIdx.x;
    const float* in; u16* out; int K, N, k0, n0;
    if (bid < 2048) {
        in = Wq; out = Wqkvb; K = 1024; N = 2048;
        k0 = (bid & 31) * 32; n0 = (bid >> 5) * 32;
    } else if (bid < 3072) {
        int b = bid - 2048;
        in = Wk; out = Wqkvb + (size_t)2048 * 1024; K = 1024; N = 1024;
        k0 = (b & 31) * 32; n0 = (b >> 5) * 32;
    } else if (bid < 4096) {
        int b = bid - 3072;
        in = Wv; out = Wqkvb + (size_t)3072 * 1024; K = 1024; N = 1024;
        k0 = (b & 31) * 32; n0 = (b >> 5) * 32;
    } else {
        int b = bid - 4096;
        in = Wo; out = Wob; K = 2048; N = 1024;
        k0 = (b & 63) * 32; n0 = (b >> 6) * 32;
    }
    for (int c = threadIdx.x; c < 1024; c += 256) {
        int k = c >> 5, n = c & 31;
        t[k][n] = f2bf(in[(size_t)(k0 + k) * N + n0 + n]);
    }
    __syncthreads();
    for (int c = threadIdx.x; c < 1024; c += 256) {
        int n = c >> 5, k = c & 31;
        out[(size_t)(n0 + n) * K + k0 + k] = t[k][n];
    }
}

// ---------------- QKV GEMM 128x128 + FUSED RMSNorm/RoPE (q,k) + V-transpose (v) ----------------
// Main loop = proven gemm_bf16_t structure (BK=64 as two BK=32 slabs). Each 128-col tile
// is exactly one head (n0 multiple of 128). Epilogue: stage C tile to LDS bf16 (reusing
// the 32KB As/Bs memory) with per-row XOR-63 col swizzle -- conflict-free for BOTH
// row-major (q/k norm) and column-major (v transpose) reads -- then:
//  q/k: per-row 64-lane shfl-reduce RMSNorm + RoPE (identical op sequence to the old
//       norm_rope kernel; reads the same bf16 values it would have read from qkvb),
//       write Qb/Kb head-major, q-scale folded.
//  v:   write Vbt[d][t] with coalesced 128B stores (same values old v_transpose copied).
// Eliminates the qkvb round-trip (-32MB write, -48MB read) and two kernel launches.
__global__ __launch_bounds__(256) void gemm_qkv_fused(const u16* __restrict__ A,
                                                      const u16* __restrict__ Bt,
                                                      const float* __restrict__ cosp,
                                                      const float* __restrict__ sinp,
                                                      const float* __restrict__ qnw,
                                                      const float* __restrict__ knw,
                                                      u16* __restrict__ Qb,
                                                      u16* __restrict__ Kb,
                                                      u16* __restrict__ Vbt,
                                                      int T, float qscale) {
    __shared__ u16 smem[16384];        // main loop: As[2][4096] | Bs[2][4096]; epilogue: Ct[128][128]
    u16* Asm = smem;                   // As[s] base = s*4096
    u16* Bsm = smem + 8192;            // Bs[s] base = s*4096
    const int K = 1024, N = 4096;
    int tid = threadIdx.x;
    int lane = tid & 63, wave = tid >> 6;
    int quad = lane >> 4, l15 = lane & 15;
    int wr = wave >> 1, wc = wave & 1;
    int m0 = blockIdx.y * 128, n0 = blockIdx.x * 128;

    f32x4 zero = {0.f, 0.f, 0.f, 0.f};
    f32x4 acc[4][4];
    for (int i = 0; i < 4; i++)
        for (int j = 0; j < 4; j++) acc[i][j] = zero;

    int r0 = 16 * wave + (lane >> 2);
    int r1 = r0 + 64;
    int ks0 = (lane & 3) ^ ((r0 >> 1) & 3);
    int ks1 = (lane & 3) ^ ((r1 >> 1) & 3);
    const u16* ga0 = A + (size_t)(m0 + r0) * K + ks0 * 8;
    const u16* ga1 = A + (size_t)(m0 + r1) * K + ks1 * 8;
    const u16* gb0 = Bt + (size_t)(n0 + r0) * K + ks0 * 8;
    const u16* gb1 = Bt + (size_t)(n0 + r1) * K + ks1 * 8;

    int swz = (quad ^ ((l15 >> 1) & 3)) * 8;

    for (int k0 = 0; k0 < K; k0 += 64) {
        __syncthreads();
        #pragma unroll
        for (int s = 0; s < 2; s++) {
            gload_lds16(ga0 + k0 + s * 32, &Asm[s * 4096 + wave * 512]);
            gload_lds16(ga1 + k0 + s * 32, &Asm[s * 4096 + (wave + 4) * 512]);
            gload_lds16(gb0 + k0 + s * 32, &Bsm[s * 4096 + wave * 512]);
            gload_lds16(gb1 + k0 + s * 32, &Bsm[s * 4096 + (wave + 4) * 512]);
        }
        __syncthreads();
        #pragma unroll
        for (int s = 0; s < 2; s++) {
            bf16x8 a[4], b[4];
            #pragma unroll
            for (int i = 0; i < 4; i++) a[i] = ld_frag(&Asm[s * 4096 + (64 * wr + 16 * i + l15) * 32 + swz]);
            #pragma unroll
            for (int j = 0; j < 4; j++) b[j] = ld_frag(&Bsm[s * 4096 + (64 * wc + 16 * j + l15) * 32 + swz]);
            #pragma unroll
            for (int i = 0; i < 4; i++)
                #pragma unroll
                for (int j = 0; j < 4; j++)
                    acc[i][j] = __builtin_amdgcn_mfma_f32_16x16x32_bf16(a[i], b[j], acc[i][j], 0, 0, 0);
        }
    }

    // ---- epilogue: C tile -> LDS bf16, swizzled Ct[row][col ^ (row&63)] ----
    __syncthreads();   // all LDS reads of As/Bs done before overwrite
    u16* Ct = smem;
    #pragma unroll
    for (int i = 0; i < 4; i++) {
        int rowb = 64 * wr + 16 * i + quad * 4;
        #pragma unroll
        for (int j = 0; j < 4; j++) {
            int col = 64 * wc + 16 * j + l15;
            #pragma unroll
            for (int r = 0; r < 4; r++) {
                int row = rowb + r;
                Ct[row * 128 + (col ^ (row & 63))] = f2bf(acc[i][j][r]);
            }
        }
    }
    __syncthreads();

    if (n0 < 3072) {
        // q/k head: per-row RMSNorm + RoPE (op sequence identical to old norm_rope)
        bool isq = n0 < 2048;
        int hh = isq ? (n0 >> 7) : ((n0 - 2048) >> 7);
        const float* w = isq ? qnw : knw;
        float outscale = isq ? qscale : 1.0f;
        u16* outp = isq ? (Qb + (size_t)hh * T * 128) : (Kb + (size_t)hh * T * 128);
        int d = lane;
        float wd1 = w[d], wd2 = w[d + 64];
        for (int rr = 0; rr < 32; rr++) {
            int row = wave * 32 + rr;
            int t = m0 + row;
            float v1 = bf2f(Ct[row * 128 + (d ^ (row & 63))]);
            float v2 = bf2f(Ct[row * 128 + ((d + 64) ^ (row & 63))]);
            float ss = v1 * v1 + v2 * v2;
            for (int off = 1; off < 64; off <<= 1) ss += __shfl_xor(ss, off);
            float inv = rsqrtf(ss * (1.f / 128.f) + 1e-6f);
            float n1 = v1 * inv * wd1, n2 = v2 * inv * wd2;
            float c = cosp[(size_t)t * 64 + d], s = sinp[(size_t)t * 64 + d];
            u16* orow = outp + (size_t)t * 128;
            orow[d] = f2bf((n1 * c - n2 * s) * outscale);
            orow[d + 64] = f2bf((n1 * s + n2 * c) * outscale);
        }
    } else {
        // v head: transpose out of LDS, coalesced 128B stores along t
        int vh = (n0 - 3072) >> 7;
        for (int dd = 0; dd < 32; dd++) {
            int dcol = wave * 32 + dd;
            u16* vrow = Vbt + ((size_t)vh * 128 + dcol) * T + m0;
            int t1 = lane, t2 = lane + 64;
            vrow[t1] = Ct[t1 * 128 + (dcol ^ (t1 & 63))];
            vrow[t2] = Ct[t2 * 128 + (dcol ^ (t2 & 63))];
        }
    }
}

// ---------------- GEMM 128x64, BK=64 (Wo) ----------------
__global__ __launch_bounds__(256) void gemm_bf16_n64(const u16* __restrict__ A,
                                                     const u16* __restrict__ Bt,
                                                     float* __restrict__ C,
                                                     int M, int N, int K) {
    __shared__ u16 As[2][128 * 32];
    __shared__ u16 Bs[2][64 * 32];
    int tid = threadIdx.x;
    int lane = tid & 63, wave = tid >> 6;
    int quad = lane >> 4, l15 = lane & 15;
    int m0 = blockIdx.y * 128, n0 = blockIdx.x * 64;

    f32x4 zero = {0.f, 0.f, 0.f, 0.f};
    f32x4 acc[2][4];
    for (int i = 0; i < 2; i++)
        for (int j = 0; j < 4; j++) acc[i][j] = zero;

    int ra0 = 32 * wave + (lane >> 2);
    int ra1 = ra0 + 16;
    int rb  = 16 * wave + (lane >> 2);
    int ksa0 = (lane & 3) ^ ((ra0 >> 1) & 3);
    int ksa1 = (lane & 3) ^ ((ra1 >> 1) & 3);
    int ksb  = (lane & 3) ^ ((rb >> 1) & 3);
    const u16* ga0 = A + (size_t)(m0 + ra0) * K + ksa0 * 8;
    const u16* ga1 = A + (size_t)(m0 + ra1) * K + ksa1 * 8;
    const u16* gb  = Bt + (size_t)(n0 + rb) * K + ksb * 8;

    int swz = (quad ^ ((l15 >> 1) & 3)) * 8;

    for (int k0 = 0; k0 < K; k0 += 64) {
        __syncthreads();
        #pragma unroll
        for (int s = 0; s < 2; s++) {
            gload_lds16(ga0 + k0 + s * 32, &As[s][(2 * wave) * 512]);
            gload_lds16(ga1 + k0 + s * 32, &As[s][(2 * wave + 1) * 512]);
            gload_lds16(gb + k0 + s * 32, &Bs[s][wave * 512]);
        }
        __syncthreads();
        #pragma unroll
        for (int s = 0; s < 2; s++) {
            bf16x8 a[2], b[4];
            #pragma unroll
            for (int i = 0; i < 2; i++) a[i] = ld_frag(&As[s][(32 * wave + 16 * i + l15) * 32 + swz]);
            #pragma unroll
            for (int j = 0; j < 4; j++) b[j] = ld_frag(&Bs[s][(16 * j + l15) * 32 + swz]);
            #pragma unroll
            for (int i = 0; i < 2; i++)
                #pragma unroll
                for (int j = 0; j < 4; j++)
                    acc[i][j] = __builtin_amdgcn_mfma_f32_16x16x32_bf16(a[i], b[j], acc[i][j], 0, 0, 0);
        }
    }
    for (int i = 0; i < 2; i++) {
        int rowb = m0 + 32 * wave + 16 * i + quad * 4;
        for (int j = 0; j < 4; j++) {
            int col = n0 + 16 * j + l15;
            for (int r = 0; r < 4; r++)
                C[(size_t)(rowb + r) * N + col] = acc[i][j][r];
        }
    }
}

// ---------------- causal MFMA flash attention, R2 exact (159.3us, verified) ----------------
// Wave (qw, sh): qw = wave&3 owns q-rows [16qw,16qw+16); sh = wave>>2 owns s-half sh of
// every 64-wide KV tile. Per-wave online softmax on its 32-s half; one flash merge per
// pass between the sh-pair through LDS (Ms/Ls + Ks-as-scratch).
__global__ __launch_bounds__(512, 4) void flash_attn(const u16* __restrict__ Qb,
                                                     const u16* __restrict__ Kb,
                                                     const u16* __restrict__ Vbt,
                                                     u16* __restrict__ attn, int T) {
    __shared__ u16 Ks[2][64 * 128];
    __shared__ u16 Vt[2][128 * 64];
    __shared__ u16 Ps[64 * 64];
    __shared__ float Ms[4][2][16];
    __shared__ float Ls[4][2][16];
    int tid = threadIdx.x;
    int lane = tid & 63, wave = tid >> 6;   // 0..7
    int qw = wave & 3, sh = wave >> 2;
    int quad = lane >> 4, l15 = lane & 15;
    int swb8 = (l15 & 7) * 8;
    int h = blockIdx.y;
    int j = (int)blockIdx.x;   // 0..31
    int kvh = h >> 1;

    const u16* kbase = Kb + (size_t)kvh * T * 128;
    const u16* vbase = Vbt + (size_t)kvh * 128 * T;

    int krow_ = lane >> 4;
    int kseg_ = lane & 15;
    int vrow_ = lane >> 3;
    int vseg_ = lane & 7;

    auto stage = [&](int s0, int b) {
        #pragma unroll
        for (int i = 0; i < 2; i++) {
            int ch = wave * 2 + i;
            int r = ch * 4 + krow_;
            int s = kseg_ ^ (r & 7);
            gload_lds16(kbase + (size_t)(s0 + r) * 128 + s * 8, &Ks[b][ch * 512]);
        }
        #pragma unroll
        for (int i = 0; i < 2; i++) {
            int ch = wave * 2 + i;
            int d = ch * 8 + vrow_;
            int s = vseg_ ^ (d & 7);
            gload_lds16(vbase + (size_t)d * T + s0 + s * 8, &Vt[b][ch * 512]);
        }
    };

    bf16x8 onesf;
    #pragma unroll
    for (int i = 0; i < 8; i++) onesf[i] = (__bf16)1.0f;
    f32x4 zero = {0.f, 0.f, 0.f, 0.f};
    const float L2E = 1.44269504f;

    for (int pass = 0; pass < 2; ++pass) {
        int qt = pass == 0 ? (63 - j) : j;
        int q0 = qt * 64;

        bf16x8 qf[4];
        {
            const u16* qp = Qb + ((size_t)h * T + q0 + 16 * qw + l15) * 128 + quad * 8;
            #pragma unroll
            for (int kk = 0; kk < 4; kk++) qf[kk] = ld_frag(qp + kk * 32);
        }

        float m_i = -3.0e38f;       // per-lane: q-row = 16*qw + l15
        f32x4 lsum = zero;          // C-layout rows: q = 16*qw + quad*4 + r
        f32x4 o[8];
        for (int dt = 0; dt < 8; dt++) o[dt] = zero;

        int ntiles = qt + 1;
        stage(0, 0);
        __syncthreads();  // tile 0 resident

        for (int it = 0; it < ntiles; ++it) {
            int b = it & 1;
            if (it + 1 < ntiles) stage((it + 1) * 64, 1 - b);  // async into other buffer
            bool diag = (it == qt);
            // diagonal tile: sh=1 waves with q-rows entirely < 32 are fully masked -> skip
            if (!(diag && sh == 1 && qw < 2)) {
                // S^T: A=K (own s-half), B=Q. scT[jt][r]: s = sh*32+jt*16+quad*4+r, q = 16qw+l15
                f32x4 scT[2];
                scT[0] = zero; scT[1] = zero;
                #pragma unroll
                for (int kk = 0; kk < 4; kk++)
                    #pragma unroll
                    for (int jt = 0; jt < 2; jt++) {
                        bf16x8 kfrag = ld_frag(&Ks[b][(sh * 32 + jt * 16 + l15) * 128 + ((kk * 32 + quad * 8) ^ swb8)]);
                        scT[jt] = __builtin_amdgcn_mfma_f32_16x16x32_bf16(kfrag, qf[kk], scT[jt], 0, 0, 0);
                    }

                if (diag) {  // mask s > q
                    int qloc = 16 * qw + l15;
                    #pragma unroll
                    for (int jt = 0; jt < 2; jt++)
                        for (int r = 0; r < 4; r++)
                            if (sh * 32 + jt * 16 + quad * 4 + r > qloc) scT[jt][r] = -1e30f;
                }

                // lane-local max over 8 scores (same q), then 2-step butterfly across quads
                float mt = scT[0][0];
                #pragma unroll
                for (int jt = 0; jt < 2; jt++)
                    for (int r = 0; r < 4; r++) mt = fmaxf(mt, scT[jt][r]);
                mt = fmaxf(mt, __shfl_xor(mt, 16));
                mt = fmaxf(mt, __shfl_xor(mt, 32));
                float mnew = fmaxf(m_i, mt);
                float alpha = __expf(m_i - mnew);
                m_i = mnew;
                float mls = mnew * L2E;

                #pragma unroll
                for (int jt = 0; jt < 2; jt++)
                    for (int r = 0; r < 4; r++)
                        scT[jt][r] = exp2f(fmaf(scT[jt][r], L2E, -mls));

                // P^T -> Ps[q][s]: wave writes its own (16q x 32s) quadrant
                {
                    int prow = 16 * qw + l15;
                    #pragma unroll
                    for (int jt = 0; jt < 2; jt++) {
                        int s8 = sh * 4 + 2 * jt + (quad >> 1);
                        uint2 wv;
                        wv.x = pack_bf16(scT[jt][1], scT[jt][0]);
                        wv.y = pack_bf16(scT[jt][3], scT[jt][2]);
                        *reinterpret_cast<uint2*>(&Ps[prow * 64 + (s8 ^ (l15 & 7)) * 8 + (quad & 1) * 4]) = wv;
                    }
                }

                // alpha-skip: rescale only when some lane's max advanced
                if (__any(alpha != 1.0f)) {
                    float av[4];
                    #pragma unroll
                    for (int r = 0; r < 4; r++) av[r] = __shfl(alpha, quad * 4 + r);
                    #pragma unroll
                    for (int r = 0; r < 4; r++) lsum[r] *= av[r];
                    #pragma unroll
                    for (int dt = 0; dt < 8; dt++)
                        for (int r = 0; r < 4; r++) o[dt][r] *= av[r];
                }

                asm volatile("s_waitcnt lgkmcnt(0)" ::: "memory");  // wave-private Ps quadrant ordering

                bf16x8 pa = ld_frag(&Ps[(16 * qw + l15) * 64 + (((sh * 4 + quad) ^ (l15 & 7)) * 8)]);
                lsum = __builtin_amdgcn_mfma_f32_16x16x32_bf16(pa, onesf, lsum, 0, 0, 0);
                #pragma unroll
                for (int dt = 0; dt < 8; dt++) {
                    bf16x8 vb = ld_frag(&Vt[b][(dt * 16 + l15) * 64 + (((sh * 4 + quad) * 8) ^ swb8)]);
                    o[dt] = __builtin_amdgcn_mfma_f32_16x16x32_bf16(pa, vb, o[dt], 0, 0, 0);
                }
            }
            __syncthreads();  // drains next-tile loads + buffer handoff
        }

        // ---- merge the two s-halves (waves sh=0/1 with same qw) ----
        if (quad == 0) Ms[qw][sh][l15] = m_i;
        if (l15 == 0) {
            #pragma unroll
            for (int r = 0; r < 4; r++) Ls[qw][sh][quad * 4 + r] = lsum[r];
        }
        __syncthreads();
        float M4[4], wS[4];
        #pragma unroll
        for (int r = 0; r < 4; r++) {
            float mS = Ms[qw][sh][quad * 4 + r];
            float mO = Ms[qw][sh ^ 1][quad * 4 + r];
            M4[r] = fmaxf(mS, mO);
            wS[r] = __expf(mS - M4[r]);
        }
        float* scr = reinterpret_cast<float*>(&Ks[0][0]);  // 32KB: [qw][d:128][q':16]
        if (sh == 1) {
            #pragma unroll
            for (int dt = 0; dt < 8; dt++)
                #pragma unroll
                for (int r = 0; r < 4; r++)
                    scr[qw * 2048 + (dt * 16 + l15) * 16 + ((quad * 4 + r) ^ l15)] = o[dt][r] * wS[r];
        }
        __syncthreads();
        if (sh == 0) {
            float inv[4];
            #pragma unroll
            for (int r = 0; r < 4; r++) {
                float mO = Ms[qw][1][quad * 4 + r];
                float wO = __expf(mO - M4[r]);
                float l = lsum[r] * wS[r] + Ls[qw][1][quad * 4 + r] * wO;
                inv[r] = 1.f / l;
            }
            #pragma unroll
            for (int dt = 0; dt < 8; dt++)
                #pragma unroll
                for (int r = 0; r < 4; r++) {
                    float val = (o[dt][r] * wS[r] +
                                 scr[qw * 2048 + (dt * 16 + l15) * 16 + ((quad * 4 + r) ^ l15)]) * inv[r];
                    int row = q0 + 16 * qw + quad * 4 + r;
                    attn[(size_t)row * NQ + h * DHEAD + dt * 16 + l15] = f2bf(val);
                }
        }
        __syncthreads();  // scr/Ms/Ls free before next pass restages Ks[0]
    }
}

extern "C" void kernel_launch(void* const* d_in, const int* in_sizes, int n_in,
                              void* d_out, int out_size, void* d_ws, size_t ws_size,
                              hipStream_t stream) {
    const float* x    = (const float*)d_in[0];
    const float* cosp = (const float*)d_in[1];
    const float* sinp = (const float*)d_in[2];
    const float* Wq   = (const float*)d_in[3];
    const float* Wk   = (const float*)d_in[4];
    const float* Wv   = (const float*)d_in[5];
    const float* Wo   = (const float*)d_in[6];
    const float* qnw  = (const float*)d_in[7];
    const float* knw  = (const float*)d_in[8];
    float* out = (float*)d_out;
    const int T = in_sizes[1] / 64;  // 4096

    char* ws = (char*)d_ws;
    size_t off = 0;
    auto alloc = [&](size_t bytes) {
        char* p = ws + off;
        off += (bytes + 255) & ~(size_t)255;
        return p;
    };
    u16*   xb     = (u16*)alloc((size_t)T * HID * 2);
    u16*   Wqkvb  = (u16*)alloc((size_t)4096 * HID * 2);
    u16*   Wob    = (u16*)alloc((size_t)HID * NQ * 2);
    u16*   Qb     = (u16*)alloc((size_t)H2 * T * DHEAD * 2);
    u16*   Kb     = (u16*)alloc((size_t)HKV * T * DHEAD * 2);
    u16*   Vbt    = (u16*)alloc((size_t)HKV * DHEAD * T * 2);
    u16*   attn   = (u16*)alloc((size_t)T * NQ * 2);

    cast_f32_bf16<<<(T * HID / 4 + 255) / 256, 256, 0, stream>>>(x, xb, T * HID / 4);
    transpose_cast_all<<<6144, 256, 0, stream>>>(Wq, Wk, Wv, Wo, Wqkvb, Wob);

    const float scale = 0.08838834764831845f;  // 128^-0.5 folded into Q
    gemm_qkv_fused<<<dim3(4096 / 128, T / 128), 256, 0, stream>>>(
        xb, Wqkvb, cosp, sinp, qnw, knw, Qb, Kb, Vbt, T, scale);

    flash_attn<<<dim3(32, H2), 512, 0, stream>>>(Qb, Kb, Vbt, attn, T);

    gemm_bf16_n64<<<dim3(HID / 64, T / 128), 256, 0, stream>>>(attn, Wob, out, T, HID, NQ);
}

// Round 10
// 318.106 us; speedup vs baseline: 1.1419x; 1.0784x over previous
//
#include <hip/hip_runtime.h>
#include <hip/hip_bf16.h>

#define H2 16
#define HKV 8
#define DHEAD 128
#define HID 1024
#define NQ 2048

typedef unsigned short u16;
typedef __bf16 bf16x8 __attribute__((ext_vector_type(8)));
typedef float f32x4 __attribute__((ext_vector_type(4)));

__device__ __forceinline__ u16 f2bf(float x) {
    unsigned int u = __float_as_uint(x);
    unsigned int r = (u + 0x7fffu + ((u >> 16) & 1u)) >> 16;
    return (u16)r;
}
__device__ __forceinline__ float bf2f(u16 x) {
    return __uint_as_float(((unsigned int)x) << 16);
}

// pack two fp32 -> (bf16(hi)<<16)|bf16(lo)
__device__ __forceinline__ unsigned int pack_bf16(float hi, float lo) {
    unsigned int a = __float_as_uint(hi) + 0x8000u;
    unsigned int b = __float_as_uint(lo) + 0x8000u;
    return __builtin_amdgcn_perm(a, b, 0x07060302u);
}

__device__ __forceinline__ bf16x8 ld_frag(const u16* p) {
    bf16x8 r;
    *reinterpret_cast<uint4*>(&r) = *reinterpret_cast<const uint4*>(p);
    return r;
}

__device__ __forceinline__ void gload_lds16(const u16* g, u16* l) {
    __builtin_amdgcn_global_load_lds((const __attribute__((address_space(1))) void*)g,
                                     (__attribute__((address_space(3))) void*)l, 16, 0, 0);
}

// ---------------- prep: weight transposes (blocks 0..6143) + x cast (blocks 6144..) ----------------
__global__ __launch_bounds__(256) void prep_all(const float* __restrict__ x,
                                                const float* __restrict__ Wq,
                                                const float* __restrict__ Wk,
                                                const float* __restrict__ Wv,
                                                const float* __restrict__ Wo,
                                                u16* __restrict__ xb,
                                                u16* __restrict__ Wqkvb,
                                                u16* __restrict__ Wob, int n4) {
    __shared__ u16 t[32][34];
    int bid = blockIdx.x;
    if (bid >= 6144) {
        int i = (bid - 6144) * 256 + threadIdx.x;
        if (i < n4) {
            float4 v = reinterpret_cast<const float4*>(x)[i];
            ushort4 o;
            o.x = f2bf(v.x); o.y = f2bf(v.y); o.z = f2bf(v.z); o.w = f2bf(v.w);
            reinterpret_cast<ushort4*>(xb)[i] = o;
        }
        return;
    }
    const float* in; u16* out; int K, N, k0, n0;
    if (bid < 2048) {
        in = Wq; out = Wqkvb; K = 1024; N = 2048;
        k0 = (bid & 31) * 32; n0 = (bid >> 5) * 32;
    } else if (bid < 3072) {
        int b = bid - 2048;
        in = Wk; out = Wqkvb + (size_t)2048 * 1024; K = 1024; N = 1024;
        k0 = (b & 31) * 32; n0 = (b >> 5) * 32;
    } else if (bid < 4096) {
        int b = bid - 3072;
        in = Wv; out = Wqkvb + (size_t)3072 * 1024; K = 1024; N = 1024;
        k0 = (b & 31) * 32; n0 = (b >> 5) * 32;
    } else {
        int b = bid - 4096;
        in = Wo; out = Wob; K = 2048; N = 1024;
        k0 = (b & 63) * 32; n0 = (b >> 6) * 32;
    }
    for (int c = threadIdx.x; c < 1024; c += 256) {
        int k = c >> 5, n = c & 31;
        t[k][n] = f2bf(in[(size_t)(k0 + k) * N + n0 + n]);
    }
    __syncthreads();
    for (int c = threadIdx.x; c < 1024; c += 256) {
        int n = c >> 5, k = c & 31;
        out[(size_t)(n0 + n) * K + k0 + k] = t[k][n];
    }
}

// ---------------- QKV GEMM 128x128 + FUSED RMSNorm/RoPE (q,k) + V-transpose (v) ----------------
// Main loop = proven gemm_bf16_t structure (BK=64 as two BK=32 slabs). Each 128-col tile
// is exactly one head. Epilogue: C tile -> LDS bf16 (XOR-63 row swizzle), then q/k blocks
// run per-row RMSNorm+RoPE (one 32-lane half-wave per row: 4 elems/lane, 5-shfl reduce;
// RoPE pairs (d,d+64)/(d+32,d+96) stay lane-local) and v blocks transpose to Vbt.
__global__ __launch_bounds__(256) void gemm_qkv_fused(const u16* __restrict__ A,
                                                      const u16* __restrict__ Bt,
                                                      const float* __restrict__ cosp,
                                                      const float* __restrict__ sinp,
                                                      const float* __restrict__ qnw,
                                                      const float* __restrict__ knw,
                                                      u16* __restrict__ Qb,
                                                      u16* __restrict__ Kb,
                                                      u16* __restrict__ Vbt,
                                                      int T, float qscale) {
    __shared__ u16 smem[16384];        // main loop: As[2][4096] | Bs[2][4096]; epilogue: Ct[128][128]
    u16* Asm = smem;
    u16* Bsm = smem + 8192;
    const int K = 1024;
    int tid = threadIdx.x;
    int lane = tid & 63, wave = tid >> 6;
    int quad = lane >> 4, l15 = lane & 15;
    int wr = wave >> 1, wc = wave & 1;
    int m0 = blockIdx.y * 128, n0 = blockIdx.x * 128;

    f32x4 zero = {0.f, 0.f, 0.f, 0.f};
    f32x4 acc[4][4];
    for (int i = 0; i < 4; i++)
        for (int j = 0; j < 4; j++) acc[i][j] = zero;

    int r0 = 16 * wave + (lane >> 2);
    int r1 = r0 + 64;
    int ks0 = (lane & 3) ^ ((r0 >> 1) & 3);
    int ks1 = (lane & 3) ^ ((r1 >> 1) & 3);
    const u16* ga0 = A + (size_t)(m0 + r0) * K + ks0 * 8;
    const u16* ga1 = A + (size_t)(m0 + r1) * K + ks1 * 8;
    const u16* gb0 = Bt + (size_t)(n0 + r0) * K + ks0 * 8;
    const u16* gb1 = Bt + (size_t)(n0 + r1) * K + ks1 * 8;

    int swz = (quad ^ ((l15 >> 1) & 3)) * 8;

    for (int k0 = 0; k0 < K; k0 += 64) {
        __syncthreads();
        #pragma unroll
        for (int s = 0; s < 2; s++) {
            gload_lds16(ga0 + k0 + s * 32, &Asm[s * 4096 + wave * 512]);
            gload_lds16(ga1 + k0 + s * 32, &Asm[s * 4096 + (wave + 4) * 512]);
            gload_lds16(gb0 + k0 + s * 32, &Bsm[s * 4096 + wave * 512]);
            gload_lds16(gb1 + k0 + s * 32, &Bsm[s * 4096 + (wave + 4) * 512]);
        }
        __syncthreads();
        #pragma unroll
        for (int s = 0; s < 2; s++) {
            bf16x8 a[4], b[4];
            #pragma unroll
            for (int i = 0; i < 4; i++) a[i] = ld_frag(&Asm[s * 4096 + (64 * wr + 16 * i + l15) * 32 + swz]);
            #pragma unroll
            for (int j = 0; j < 4; j++) b[j] = ld_frag(&Bsm[s * 4096 + (64 * wc + 16 * j + l15) * 32 + swz]);
            #pragma unroll
            for (int i = 0; i < 4; i++)
                #pragma unroll
                for (int j = 0; j < 4; j++)
                    acc[i][j] = __builtin_amdgcn_mfma_f32_16x16x32_bf16(a[i], b[j], acc[i][j], 0, 0, 0);
        }
    }

    // ---- epilogue: C tile -> LDS bf16, swizzled Ct[row][col ^ (row&63)] ----
    __syncthreads();   // all LDS reads of As/Bs done before overwrite
    u16* Ct = smem;
    #pragma unroll
    for (int i = 0; i < 4; i++) {
        int rowb = 64 * wr + 16 * i + quad * 4;
        #pragma unroll
        for (int j = 0; j < 4; j++) {
            int col = 64 * wc + 16 * j + l15;
            #pragma unroll
            for (int r = 0; r < 4; r++) {
                int row = rowb + r;
                Ct[row * 128 + (col ^ (row & 63))] = f2bf(acc[i][j][r]);
            }
        }
    }
    __syncthreads();

    if (n0 < 3072) {
        // q/k head: one 32-lane half-wave per row; lane holds cols {d, d+32, d+64, d+96}
        bool isq = n0 < 2048;
        int hh = isq ? (n0 >> 7) : ((n0 - 2048) >> 7);
        const float* w = isq ? qnw : knw;
        float outscale = isq ? qscale : 1.0f;
        u16* outp = isq ? (Qb + (size_t)hh * T * 128) : (Kb + (size_t)hh * T * 128);
        int l32 = lane & 31, hl = lane >> 5;
        float w0 = w[l32], w1 = w[l32 + 32], w2 = w[l32 + 64], w3 = w[l32 + 96];
        for (int rr = 0; rr < 16; rr++) {
            int row = wave * 32 + rr * 2 + hl;
            int t = m0 + row;
            int rx = row & 63;
            float v0 = bf2f(Ct[row * 128 + (l32 ^ rx)]);
            float v1 = bf2f(Ct[row * 128 + ((l32 + 32) ^ rx)]);
            float v2 = bf2f(Ct[row * 128 + ((l32 + 64) ^ rx)]);
            float v3 = bf2f(Ct[row * 128 + ((l32 + 96) ^ rx)]);
            float ss = (v0 * v0 + v2 * v2) + (v1 * v1 + v3 * v3);
            #pragma unroll
            for (int off = 1; off < 32; off <<= 1) ss += __shfl_xor(ss, off);
            float inv = rsqrtf(ss * (1.f / 128.f) + 1e-6f);
            float nv0 = v0 * inv * w0, nv1 = v1 * inv * w1;
            float nv2 = v2 * inv * w2, nv3 = v3 * inv * w3;
            float c0 = cosp[(size_t)t * 64 + l32], s0 = sinp[(size_t)t * 64 + l32];
            float c1 = cosp[(size_t)t * 64 + l32 + 32], s1 = sinp[(size_t)t * 64 + l32 + 32];
            u16* orow = outp + (size_t)t * 128;
            orow[l32]      = f2bf((nv0 * c0 - nv2 * s0) * outscale);
            orow[l32 + 64] = f2bf((nv0 * s0 + nv2 * c0) * outscale);
            orow[l32 + 32] = f2bf((nv1 * c1 - nv3 * s1) * outscale);
            orow[l32 + 96] = f2bf((nv1 * s1 + nv3 * c1) * outscale);
        }
    } else {
        // v head: transpose out of LDS, coalesced 128B stores along t
        int vh = (n0 - 3072) >> 7;
        for (int dd = 0; dd < 32; dd++) {
            int dcol = wave * 32 + dd;
            u16* vrow = Vbt + ((size_t)vh * 128 + dcol) * T + m0;
            int t1 = lane, t2 = lane + 64;
            vrow[t1] = Ct[t1 * 128 + (dcol ^ (t1 & 63))];
            vrow[t2] = Ct[t2 * 128 + (dcol ^ (t2 & 63))];
        }
    }
}

// ---------------- GEMM 128x64, BK=128 (four BK=32 slabs): halved barrier count (Wo) ----------------
__global__ __launch_bounds__(256) void gemm_bf16_n64(const u16* __restrict__ A,
                                                     const u16* __restrict__ Bt,
                                                     float* __restrict__ C,
                                                     int M, int N, int K) {
    __shared__ u16 As[4][128 * 32];
    __shared__ u16 Bs[4][64 * 32];
    int tid = threadIdx.x;
    int lane = tid & 63, wave = tid >> 6;
    int quad = lane >> 4, l15 = lane & 15;
    int m0 = blockIdx.y * 128, n0 = blockIdx.x * 64;

    f32x4 zero = {0.f, 0.f, 0.f, 0.f};
    f32x4 acc[2][4];
    for (int i = 0; i < 2; i++)
        for (int j = 0; j < 4; j++) acc[i][j] = zero;

    int ra0 = 32 * wave + (lane >> 2);
    int ra1 = ra0 + 16;
    int rb  = 16 * wave + (lane >> 2);
    int ksa0 = (lane & 3) ^ ((ra0 >> 1) & 3);
    int ksa1 = (lane & 3) ^ ((ra1 >> 1) & 3);
    int ksb  = (lane & 3) ^ ((rb >> 1) & 3);
    const u16* ga0 = A + (size_t)(m0 + ra0) * K + ksa0 * 8;
    const u16* ga1 = A + (size_t)(m0 + ra1) * K + ksa1 * 8;
    const u16* gb  = Bt + (size_t)(n0 + rb) * K + ksb * 8;

    int swz = (quad ^ ((l15 >> 1) & 3)) * 8;

    for (int k0 = 0; k0 < K; k0 += 128) {
        __syncthreads();
        #pragma unroll
        for (int s = 0; s < 4; s++) {
            gload_lds16(ga0 + k0 + s * 32, &As[s][(2 * wave) * 512]);
            gload_lds16(ga1 + k0 + s * 32, &As[s][(2 * wave + 1) * 512]);
            gload_lds16(gb + k0 + s * 32, &Bs[s][wave * 512]);
        }
        __syncthreads();
        #pragma unroll
        for (int s = 0; s < 4; s++) {
            bf16x8 a[2], b[4];
            #pragma unroll
            for (int i = 0; i < 2; i++) a[i] = ld_frag(&As[s][(32 * wave + 16 * i + l15) * 32 + swz]);
            #pragma unroll
            for (int j = 0; j < 4; j++) b[j] = ld_frag(&Bs[s][(16 * j + l15) * 32 + swz]);
            #pragma unroll
            for (int i = 0; i < 2; i++)
                #pragma unroll
                for (int j = 0; j < 4; j++)
                    acc[i][j] = __builtin_amdgcn_mfma_f32_16x16x32_bf16(a[i], b[j], acc[i][j], 0, 0, 0);
        }
    }
    for (int i = 0; i < 2; i++) {
        int rowb = m0 + 32 * wave + 16 * i + quad * 4;
        for (int j = 0; j < 4; j++) {
            int col = n0 + 16 * j + l15;
            for (int r = 0; r < 4; r++)
                C[(size_t)(rowb + r) * N + col] = acc[i][j][r];
        }
    }
}

// ---------------- causal MFMA flash attention, R2 exact (159-164us, verified) ----------------
__global__ __launch_bounds__(512, 4) void flash_attn(const u16* __restrict__ Qb,
                                                     const u16* __restrict__ Kb,
                                                     const u16* __restrict__ Vbt,
                                                     u16* __restrict__ attn, int T) {
    __shared__ u16 Ks[2][64 * 128];
    __shared__ u16 Vt[2][128 * 64];
    __shared__ u16 Ps[64 * 64];
    __shared__ float Ms[4][2][16];
    __shared__ float Ls[4][2][16];
    int tid = threadIdx.x;
    int lane = tid & 63, wave = tid >> 6;   // 0..7
    int qw = wave & 3, sh = wave >> 2;
    int quad = lane >> 4, l15 = lane & 15;
    int swb8 = (l15 & 7) * 8;
    int h = blockIdx.y;
    int j = (int)blockIdx.x;   // 0..31
    int kvh = h >> 1;

    const u16* kbase = Kb + (size_t)kvh * T * 128;
    const u16* vbase = Vbt + (size_t)kvh * 128 * T;

    int krow_ = lane >> 4;
    int kseg_ = lane & 15;
    int vrow_ = lane >> 3;
    int vseg_ = lane & 7;

    auto stage = [&](int s0, int b) {
        #pragma unroll
        for (int i = 0; i < 2; i++) {
            int ch = wave * 2 + i;
            int r = ch * 4 + krow_;
            int s = kseg_ ^ (r & 7);
            gload_lds16(kbase + (size_t)(s0 + r) * 128 + s * 8, &Ks[b][ch * 512]);
        }
        #pragma unroll
        for (int i = 0; i < 2; i++) {
            int ch = wave * 2 + i;
            int d = ch * 8 + vrow_;
            int s = vseg_ ^ (d & 7);
            gload_lds16(vbase + (size_t)d * T + s0 + s * 8, &Vt[b][ch * 512]);
        }
    };

    bf16x8 onesf;
    #pragma unroll
    for (int i = 0; i < 8; i++) onesf[i] = (__bf16)1.0f;
    f32x4 zero = {0.f, 0.f, 0.f, 0.f};
    const float L2E = 1.44269504f;

    for (int pass = 0; pass < 2; ++pass) {
        int qt = pass == 0 ? (63 - j) : j;
        int q0 = qt * 64;

        bf16x8 qf[4];
        {
            const u16* qp = Qb + ((size_t)h * T + q0 + 16 * qw + l15) * 128 + quad * 8;
            #pragma unroll
            for (int kk = 0; kk < 4; kk++) qf[kk] = ld_frag(qp + kk * 32);
        }

        float m_i = -3.0e38f;       // per-lane: q-row = 16*qw + l15
        f32x4 lsum = zero;          // C-layout rows: q = 16*qw + quad*4 + r
        f32x4 o[8];
        for (int dt = 0; dt < 8; dt++) o[dt] = zero;

        int ntiles = qt + 1;
        stage(0, 0);
        __syncthreads();  // tile 0 resident

        for (int it = 0; it < ntiles; ++it) {
            int b = it & 1;
            if (it + 1 < ntiles) stage((it + 1) * 64, 1 - b);  // async into other buffer
            bool diag = (it == qt);
            // diagonal tile: sh=1 waves with q-rows entirely < 32 are fully masked -> skip
            if (!(diag && sh == 1 && qw < 2)) {
                // S^T: A=K (own s-half), B=Q. scT[jt][r]: s = sh*32+jt*16+quad*4+r, q = 16qw+l15
                f32x4 scT[2];
                scT[0] = zero; scT[1] = zero;
                #pragma unroll
                for (int kk = 0; kk < 4; kk++)
                    #pragma unroll
                    for (int jt = 0; jt < 2; jt++) {
                        bf16x8 kfrag = ld_frag(&Ks[b][(sh * 32 + jt * 16 + l15) * 128 + ((kk * 32 + quad * 8) ^ swb8)]);
                        scT[jt] = __builtin_amdgcn_mfma_f32_16x16x32_bf16(kfrag, qf[kk], scT[jt], 0, 0, 0);
                    }

                if (diag) {  // mask s > q
                    int qloc = 16 * qw + l15;
                    #pragma unroll
                    for (int jt = 0; jt < 2; jt++)
                        for (int r = 0; r < 4; r++)
                            if (sh * 32 + jt * 16 + quad * 4 + r > qloc) scT[jt][r] = -1e30f;
                }

                // lane-local max over 8 scores (same q), then 2-step butterfly across quads
                float mt = scT[0][0];
                #pragma unroll
                for (int jt = 0; jt < 2; jt++)
                    for (int r = 0; r < 4; r++) mt = fmaxf(mt, scT[jt][r]);
                mt = fmaxf(mt, __shfl_xor(mt, 16));
                mt = fmaxf(mt, __shfl_xor(mt, 32));
                float mnew = fmaxf(m_i, mt);
                float alpha = __expf(m_i - mnew);
                m_i = mnew;
                float mls = mnew * L2E;

                #pragma unroll
                for (int jt = 0; jt < 2; jt++)
                    for (int r = 0; r < 4; r++)
                        scT[jt][r] = exp2f(fmaf(scT[jt][r], L2E, -mls));

                // P^T -> Ps[q][s]: wave writes its own (16q x 32s) quadrant
                {
                    int prow = 16 * qw + l15;
                    #pragma unroll
                    for (int jt = 0; jt < 2; jt++) {
                        int s8 = sh * 4 + 2 * jt + (quad >> 1);
                        uint2 wv;
                        wv.x = pack_bf16(scT[jt][1], scT[jt][0]);
                        wv.y = pack_bf16(scT[jt][3], scT[jt][2]);
                        *reinterpret_cast<uint2*>(&Ps[prow * 64 + (s8 ^ (l15 & 7)) * 8 + (quad & 1) * 4]) = wv;
                    }
                }

                // alpha-skip: rescale only when some lane's max advanced
                if (__any(alpha != 1.0f)) {
                    float av[4];
                    #pragma unroll
                    for (int r = 0; r < 4; r++) av[r] = __shfl(alpha, quad * 4 + r);
                    #pragma unroll
                    for (int r = 0; r < 4; r++) lsum[r] *= av[r];
                    #pragma unroll
                    for (int dt = 0; dt < 8; dt++)
                        for (int r = 0; r < 4; r++) o[dt][r] *= av[r];
                }

                asm volatile("s_waitcnt lgkmcnt(0)" ::: "memory");  // wave-private Ps quadrant ordering

                bf16x8 pa = ld_frag(&Ps[(16 * qw + l15) * 64 + (((sh * 4 + quad) ^ (l15 & 7)) * 8)]);
                lsum = __builtin_amdgcn_mfma_f32_16x16x32_bf16(pa, onesf, lsum, 0, 0, 0);
                #pragma unroll
                for (int dt = 0; dt < 8; dt++) {
                    bf16x8 vb = ld_frag(&Vt[b][(dt * 16 + l15) * 64 + (((sh * 4 + quad) * 8) ^ swb8)]);
                    o[dt] = __builtin_amdgcn_mfma_f32_16x16x32_bf16(pa, vb, o[dt], 0, 0, 0);
                }
            }
            __syncthreads();  // drains next-tile loads + buffer handoff
        }

        // ---- merge the two s-halves (waves sh=0/1 with same qw) ----
        if (quad == 0) Ms[qw][sh][l15] = m_i;
        if (l15 == 0) {
            #pragma unroll
            for (int r = 0; r < 4; r++) Ls[qw][sh][quad * 4 + r] = lsum[r];
        }
        __syncthreads();
        float M4[4], wS[4];
        #pragma unroll
        for (int r = 0; r < 4; r++) {
            float mS = Ms[qw][sh][quad * 4 + r];
            float mO = Ms[qw][sh ^ 1][quad * 4 + r];
            M4[r] = fmaxf(mS, mO);
            wS[r] = __expf(mS - M4[r]);
        }
        float* scr = reinterpret_cast<float*>(&Ks[0][0]);  // 32KB: [qw][d:128][q':16]
        if (sh == 1) {
            #pragma unroll
            for (int dt = 0; dt < 8; dt++)
                #pragma unroll
                for (int r = 0; r < 4; r++)
                    scr[qw * 2048 + (dt * 16 + l15) * 16 + ((quad * 4 + r) ^ l15)] = o[dt][r] * wS[r];
        }
        __syncthreads();
        if (sh == 0) {
            float inv[4];
            #pragma unroll
            for (int r = 0; r < 4; r++) {
                float mO = Ms[qw][1][quad * 4 + r];
                float wO = __expf(mO - M4[r]);
                float l = lsum[r] * wS[r] + Ls[qw][1][quad * 4 + r] * wO;
                inv[r] = 1.f / l;
            }
            #pragma unroll
            for (int dt = 0; dt < 8; dt++)
                #pragma unroll
                for (int r = 0; r < 4; r++) {
                    float val = (o[dt][r] * wS[r] +
                                 scr[qw * 2048 + (dt * 16 + l15) * 16 + ((quad * 4 + r) ^ l15)]) * inv[r];
                    int row = q0 + 16 * qw + quad * 4 + r;
                    attn[(size_t)row * NQ + h * DHEAD + dt * 16 + l15] = f2bf(val);
                }
        }
        __syncthreads();  // scr/Ms/Ls free before next pass restages Ks[0]
    }
}

extern "C" void kernel_launch(void* const* d_in, const int* in_sizes, int n_in,
                              void* d_out, int out_size, void* d_ws, size_t ws_size,
                              hipStream_t stream) {
    const float* x    = (const float*)d_in[0];
    const float* cosp = (const float*)d_in[1];
    const float* sinp = (const float*)d_in[2];
    const float* Wq   = (const float*)d_in[3];
    const float* Wk   = (const float*)d_in[4];
    const float* Wv   = (const float*)d_in[5];
    const float* Wo   = (const float*)d_in[6];
    const float* qnw  = (const float*)d_in[7];
    const float* knw  = (const float*)d_in[8];
    float* out = (float*)d_out;
    const int T = in_sizes[1] / 64;  // 4096

    char* ws = (char*)d_ws;
    size_t off = 0;
    auto alloc = [&](size_t bytes) {
        char* p = ws + off;
        off += (bytes + 255) & ~(size_t)255;
        return p;
    };
    u16*   xb     = (u16*)alloc((size_t)T * HID * 2);
    u16*   Wqkvb  = (u16*)alloc((size_t)4096 * HID * 2);
    u16*   Wob    = (u16*)alloc((size_t)HID * NQ * 2);
    u16*   Qb     = (u16*)alloc((size_t)H2 * T * DHEAD * 2);
    u16*   Kb     = (u16*)alloc((size_t)HKV * T * DHEAD * 2);
    u16*   Vbt    = (u16*)alloc((size_t)HKV * DHEAD * T * 2);
    u16*   attn   = (u16*)alloc((size_t)T * NQ * 2);

    int n4 = T * HID / 4;
    prep_all<<<6144 + (n4 + 255) / 256, 256, 0, stream>>>(x, Wq, Wk, Wv, Wo, xb, Wqkvb, Wob, n4);

    const float scale = 0.08838834764831845f;  // 128^-0.5 folded into Q
    gemm_qkv_fused<<<dim3(4096 / 128, T / 128), 256, 0, stream>>>(
        xb, Wqkvb, cosp, sinp, qnw, knw, Qb, Kb, Vbt, T, scale);

    flash_attn<<<dim3(32, H2), 512, 0, stream>>>(Qb, Kb, Vbt, attn, T);

    gemm_bf16_n64<<<dim3(HID / 64, T / 128), 256, 0, stream>>>(attn, Wob, out, T, HID, NQ);
}